// Round 1
// baseline (131434.131 us; speedup 1.0000x reference)
//
#include <hip/hip_runtime.h>
#include <stdint.h>

typedef unsigned int u32;
typedef unsigned short u16;

#define L_VERTS 65536
#define N_EDGES 130560
#define N_NODES 131071   // 2*L - 1

// ---------------- radix sort (stable LSD, 4 passes x 8 bits) ----------------
#define NB 255    // sort blocks
#define TPB 64    // threads per sort block
#define IPT 8     // items per thread
#define IPB 512   // items per block (255*512 = 130560 exactly)

__global__ void init_keys(const float* __restrict__ w, u32* __restrict__ keys, u32* __restrict__ vals){
  int i = blockIdx.x*blockDim.x + threadIdx.x;
  if(i < N_EDGES){ keys[i] = __float_as_uint(w[i]); vals[i] = (u32)i; } // weights >= 0 -> uint order == float order
}

__global__ void radix_hist(const u32* __restrict__ keys, u32* __restrict__ histG, int shift){
  __shared__ u32 h[256];
  for(int i=threadIdx.x;i<256;i+=TPB) h[i]=0;
  __syncthreads();
  int base = blockIdx.x*IPB + threadIdx.x*IPT;
  #pragma unroll
  for(int i=0;i<IPT;i++){
    u32 d=(keys[base+i]>>shift)&255u;
    atomicAdd(&h[d],1u);
  }
  __syncthreads();
  for(int i=threadIdx.x;i<256;i+=TPB) histG[i*NB+blockIdx.x]=h[i];  // digit-major
}

__global__ void radix_scan(u32* histG){
  const int M = 256*NB;
  __shared__ u32 sums[1024];
  int t=threadIdx.x; int s=t*64; u32 acc=0;
  for(int i=0;i<64;i++){int idx=s+i; if(idx<M) acc+=histG[idx];}
  sums[t]=acc; __syncthreads();
  for(int off=1; off<1024; off<<=1){
    u32 v=(t>=off)?sums[t-off]:0u;
    __syncthreads();
    sums[t]+=v;
    __syncthreads();
  }
  u32 run = (t==0)?0u:sums[t-1];
  for(int i=0;i<64;i++){int idx=s+i; if(idx<M){u32 v=histG[idx]; histG[idx]=run; run+=v;}}
}

__global__ void radix_scatter(const u32* __restrict__ keys,const u32* __restrict__ vals,
                              u32* __restrict__ okeys,u32* __restrict__ ovals,
                              const u32* __restrict__ histG,int shift){
  __shared__ u16 thoff[256][TPB];   // 32 KiB
  int t=threadIdx.x;
  for(int d=t;d<256;d+=TPB) for(int j=0;j<TPB;j++) thoff[d][j]=0;
  __syncthreads();
  int base = blockIdx.x*IPB + t*IPT;
  u32 myk[IPT], myv[IPT];
  #pragma unroll
  for(int i=0;i<IPT;i++){
    myk[i]=keys[base+i]; myv[i]=vals[base+i];
    u32 d=(myk[i]>>shift)&255u; thoff[d][t]++;
  }
  __syncthreads();
  // exclusive scan across threads, per digit (thread t owns digits 4t..4t+3)
  for(int dd=0;dd<4;dd++){
    int d=t*4+dd; u32 run=0;
    for(int j=0;j<TPB;j++){ u32 v=thoff[d][j]; thoff[d][j]=(u16)run; run+=v; }
  }
  __syncthreads();
  #pragma unroll
  for(int i=0;i<IPT;i++){
    u32 d=(myk[i]>>shift)&255u;
    u32 pos = histG[d*NB+blockIdx.x] + (u32)thoff[d][t];
    thoff[d][t]++;                       // stable within thread
    okeys[pos]=myk[i]; ovals[pos]=myv[i];
  }
}

// ---------------- tree build ----------------
__global__ void init_tree(u32* parent, float* alt, float* szf, u32* canon, u32* szu){
  int i=blockIdx.x*blockDim.x+threadIdx.x;
  if(i<N_NODES){ parent[i]=(u32)i; alt[i]=0.f; szf[i]=(i<L_VERTS)?1.f:0.f; }
  if(i<L_VERTS){ canon[i]=(u32)i; szu[i]=1u; }
}

// Single-thread Kruskal (validation anchor; to be replaced by chunk-parallel build).
__global__ void __launch_bounds__(64) kruskal_serial(
    const u32* __restrict__ order, const float* __restrict__ w,
    const int* __restrict__ src, const int* __restrict__ dst,
    u32* uf, u32* canon, u32* szu,
    u32* parent, float* alt, float* szf){
  int t=threadIdx.x;
  for(int i=t;i<L_VERTS;i+=64) uf[i]=(u32)i;
  __syncthreads();
  if(t!=0) return;
  u32 nid=L_VERTS;
  // software-pipeline the independent edge loads ahead of the dependent finds
  u32 e_n=order[0]; u32 a_n=(u32)src[e_n], b_n=(u32)dst[e_n];
  for(int p=0;p<N_EDGES;p++){
    u32 e=e_n; u32 ra=a_n, rb=b_n;
    if(p+1<N_EDGES){ u32 en=order[p+1]; e_n=en; a_n=(u32)src[en]; b_n=(u32)dst[en]; }
    // find with path halving
    while(true){u32 pa=uf[ra]; if(pa==ra)break; u32 g=uf[pa]; uf[ra]=g; ra=g;}
    while(true){u32 pb=uf[rb]; if(pb==rb)break; u32 g=uf[pb]; uf[rb]=g; rb=g;}
    if(ra==rb) continue;
    u32 ca=canon[ra], cb=canon[rb];
    parent[ca]=nid; parent[cb]=nid;
    u32 sa=szu[ra], sb=szu[rb];
    u32 s=sa+sb;
    alt[nid]=w[e]; szf[nid]=(float)s;
    if(sa>=sb){ uf[rb]=ra; szu[ra]=s; canon[ra]=nid; }
    else      { uf[ra]=rb; szu[rb]=s; canon[rb]=nid; }
    nid++;
  }
}

// ---------------- softarea ----------------
__device__ __forceinline__ float sigmoidf_(float z){ return 1.0f/(1.0f+__expf(-z)); }

__global__ void out_init(float* out){
  int i=blockIdx.x*blockDim.x+threadIdx.x;
  if(i<N_NODES) out[i] = (i<L_VERTS)?0.5f:0.0f;   // inside[:L] += 0.5 (leaf self term)
}

// outside(n) = sum over ancestors a (starting at parent): (size(a)-size(prev)) * sigmoid(alt(n)-alt(a))
__global__ void outside_kernel(const u32* __restrict__ parent, const float* __restrict__ alt,
                               const float* __restrict__ szf, float* __restrict__ out){
  int n=blockIdx.x*blockDim.x+threadIdx.x;
  if(n>=N_NODES) return;
  float an=alt[n];
  float acc=0.f;
  u32 child=(u32)n;
  float szc=szf[child];
  while(true){
    u32 a=parent[child];
    if(a==child) break;
    float sza=szf[a];
    acc += (sza-szc)*sigmoidf_(an-alt[a]);
    child=a; szc=sza;
  }
  out[n]+=acc;
}

// inside: each leaf x contributes sigmoid(alt(a)-alt(parent(x))) to every proper ancestor a
__global__ void inside_kernel(const u32* __restrict__ parent, const float* __restrict__ alt,
                              float* __restrict__ out){
  int x=blockIdx.x*blockDim.x+threadIdx.x;
  if(x>=L_VERTS) return;
  u32 a=parent[x];
  float b=alt[a];
  while(true){
    atomicAdd(&out[a], sigmoidf_(alt[a]-b));
    u32 nx=parent[a];
    if(nx==a) break;
    a=nx;
  }
}

// ---------------- launch ----------------
extern "C" void kernel_launch(void* const* d_in, const int* in_sizes, int n_in,
                              void* d_out, int out_size, void* d_ws, size_t ws_size,
                              hipStream_t stream){
  (void)in_sizes; (void)n_in; (void)out_size; (void)ws_size;
  const float* w  = (const float*)d_in[0];
  const int* src  = (const int*)d_in[1];
  const int* dst  = (const int*)d_in[2];
  float* out = (float*)d_out;

  char* ws = (char*)d_ws;
  size_t off=0;
  auto alloc=[&](size_t bytes)->void*{ void* p = ws+off; off += (bytes+511)&~(size_t)511; return p; };
  u32* keys0=(u32*)alloc(N_EDGES*4);
  u32* keys1=(u32*)alloc(N_EDGES*4);
  u32* vals0=(u32*)alloc(N_EDGES*4);
  u32* vals1=(u32*)alloc(N_EDGES*4);
  u32* histG=(u32*)alloc(256*NB*4);
  u32* uf   =(u32*)alloc(L_VERTS*4);
  u32* canon=(u32*)alloc(L_VERTS*4);
  u32* szu  =(u32*)alloc(L_VERTS*4);
  u32* parent=(u32*)alloc(N_NODES*4);
  float* alt =(float*)alloc(N_NODES*4);
  float* szf =(float*)alloc(N_NODES*4);

  init_keys<<<(N_EDGES+255)/256,256,0,stream>>>(w,keys0,vals0);
  for(int pass=0;pass<4;pass++){
    const u32* ik = (pass&1)?keys1:keys0;
    const u32* iv = (pass&1)?vals1:vals0;
    u32* ok = (pass&1)?keys0:keys1;
    u32* ov = (pass&1)?vals0:vals1;
    int shift=pass*8;
    radix_hist   <<<NB,TPB,0,stream>>>(ik,histG,shift);
    radix_scan   <<<1,1024,0,stream>>>(histG);
    radix_scatter<<<NB,TPB,0,stream>>>(ik,iv,ok,ov,histG,shift);
  }
  // after 4 passes sorted (key,val) are back in keys0/vals0
  init_tree<<<(N_NODES+255)/256,256,0,stream>>>(parent,alt,szf,canon,szu);
  kruskal_serial<<<1,64,0,stream>>>(vals0,w,src,dst,uf,canon,szu,parent,alt,szf);
  out_init<<<(N_NODES+255)/256,256,0,stream>>>(out);
  outside_kernel<<<(N_NODES+255)/256,256,0,stream>>>(parent,alt,szf,out);
  inside_kernel<<<(L_VERTS+255)/256,256,0,stream>>>(parent,alt,out);
}

// Round 4
// 38146.979 us; speedup vs baseline: 3.4455x; 3.4455x over previous
//
#include <hip/hip_runtime.h>
#include <stdint.h>

typedef unsigned int u32;
typedef unsigned short u16;

#define L_VERTS 65536
#define N_EDGES 130560
#define N_NODES 131071   // 2*L - 1
#define PMASK   0x1FFFFu // 17-bit node id mask inside packed parent

// chunked-parallel tree build: 170 chunks x 768 edges = 130560
#define CCH 170
#define SCH 768
#define MAXSV 1536

// ---------------- radix sort (stable LSD, index ping-pong, gathered keys) ----
#define NB 255
#define TPB 64
#define IPT 8
#define IPB 512

__global__ void init_keys(const float* __restrict__ w, u32* __restrict__ keys, u32* __restrict__ vals){
  int i = blockIdx.x*blockDim.x + threadIdx.x;
  if(i < N_EDGES){ keys[i] = __float_as_uint(w[i]); vals[i] = (u32)i; } // w>=0 -> uint order == float order
}

__global__ void radix_hist(const u32* __restrict__ idx, const u32* __restrict__ keys,
                           u32* __restrict__ histG, int shift){
  __shared__ u32 h[256];
  for(int i=threadIdx.x;i<256;i+=TPB) h[i]=0;
  __syncthreads();
  int base = blockIdx.x*IPB + threadIdx.x*IPT;
  #pragma unroll
  for(int i=0;i<IPT;i++){
    u32 e = idx[base+i];
    u32 d = (keys[e]>>shift)&255u;
    atomicAdd(&h[d],1u);
  }
  __syncthreads();
  for(int i=threadIdx.x;i<256;i+=TPB) histG[i*NB+blockIdx.x]=h[i];  // digit-major
}

__global__ void radix_scan(u32* histG){
  const int M = 256*NB;
  __shared__ u32 sums[1024];
  int t=threadIdx.x; int s=t*64; u32 acc=0;
  for(int i=0;i<64;i++){int id=s+i; if(id<M) acc+=histG[id];}
  sums[t]=acc; __syncthreads();
  for(int off=1; off<1024; off<<=1){
    u32 v=(t>=off)?sums[t-off]:0u;
    __syncthreads();
    sums[t]+=v;
    __syncthreads();
  }
  u32 run = (t==0)?0u:sums[t-1];
  for(int i=0;i<64;i++){int id=s+i; if(id<M){u32 v=histG[id]; histG[id]=run; run+=v;}}
}

__global__ void radix_scatter(const u32* __restrict__ idxIn, const u32* __restrict__ keys,
                              u32* __restrict__ idxOut, const u32* __restrict__ histG, int shift){
  __shared__ u16 thoff[256][TPB];
  int t=threadIdx.x;
  for(int d=t;d<256;d+=TPB) for(int j=0;j<TPB;j++) thoff[d][j]=0;
  __syncthreads();
  int base = blockIdx.x*IPB + t*IPT;
  u32 myv[IPT]; u32 myd[IPT];
  #pragma unroll
  for(int i=0;i<IPT;i++){
    myv[i]=idxIn[base+i];
    myd[i]=(keys[myv[i]]>>shift)&255u;
    thoff[myd[i]][t]++;
  }
  __syncthreads();
  for(int dd=0;dd<4;dd++){
    int d=t*4+dd; u32 run=0;
    for(int j=0;j<TPB;j++){ u32 v=thoff[d][j]; thoff[d][j]=(u16)run; run+=v; }
  }
  __syncthreads();
  #pragma unroll
  for(int i=0;i<IPT;i++){
    u32 d=myd[i];
    u32 pos = histG[d*NB+blockIdx.x] + (u32)thoff[d][t];
    thoff[d][t]++;                       // stable within thread
    idxOut[pos]=myv[i];
  }
}

// ---------------- init ----------------
__global__ void init_all(u32* ufG,u32* szG,u16* canonTop16,u32* parent,float* alt,u32* hotCnt){
  int i=blockIdx.x*blockDim.x+threadIdx.x;
  if(i<N_NODES){ parent[i]=(u32)i; alt[i]=0.f; }
  if(i<L_VERTS){ ufG[i]=(u32)i; szG[i]=1u; canonTop16[i]=0xFFFFu; } // 0xFFFF: top == leaf itself
  if(i==0) *hotCnt=0u;
}

__device__ __forceinline__ u32 ald(u32* p){
  return __hip_atomic_load(p, __ATOMIC_RELAXED, __HIP_MEMORY_SCOPE_AGENT);
}
__device__ __forceinline__ void ast(u32* p, u32 v){
  __hip_atomic_store(p, v, __ATOMIC_RELAXED, __HIP_MEMORY_SCOPE_AGENT);
}

// ---------------- P1: checkpoints + global CC (1 block x 1024) ---------------
__global__ void __launch_bounds__(1024) p1_checkpoints(
    const u32* __restrict__ order, const int* __restrict__ srcv, const int* __restrict__ dstv,
    u32* ufG, u32* szG, u16* lid16, u16* svroot16, u16* svsize16, u16* svnext16, u32* mG)
{
  __shared__ u32 hkey[4096];
  __shared__ u16 hval[4096];
  __shared__ u32 mcnt;
  int t = threadIdx.x;
  for(int k=0;k<CCH;k++){
    for(int i=t;i<4096;i+=1024) hkey[i]=0xFFFFFFFFu;
    if(t==0) mcnt=0u;
    __syncthreads();
    int base = k*SCH;
    u32 myr[2]; int myslot[2]; int myclaim[2]; int mycnt=0;
    for(int i=t;i<2*SCH;i+=1024){
      int p = base + (i>>1);
      u32 e = order[p];
      u32 v = (i&1)? (u32)dstv[e] : (u32)srcv[e];
      u32 x=v;   // find w/ halving (no concurrent hooks in this phase)
      while(true){ u32 px=ald(&ufG[x]); if(px==x)break; u32 g=ald(&ufG[px]); if(g!=px) ast(&ufG[x],g); x=g; }
      u32 r=x;
      u32 h=(r*2654435761u)>>20;   // [0,4096)
      int slot=0; int claim=0;
      while(true){
        u32 old=atomicCAS(&hkey[h],0xFFFFFFFFu,r);
        if(old==0xFFFFFFFFu){slot=(int)h;claim=1;break;}
        if(old==r){slot=(int)h;break;}
        h=(h+1)&4095u;
      }
      myr[mycnt]=r; myslot[mycnt]=slot; myclaim[mycnt]=claim; mycnt++;
    }
    __syncthreads();
    for(int c=0;c<mycnt;c++) if(myclaim[c]){
      u32 id=atomicAdd(&mcnt,1u);
      hval[myslot[c]]=(u16)id;
      svroot16[k*MAXSV+id]=(u16)myr[c];
      svsize16[k*MAXSV+id]=(u16)(ald(&szG[myr[c]])-1u);  // size-1 fits u16
    }
    __syncthreads();
    {
      int c=0;
      for(int i=t;i<2*SCH;i+=1024){ lid16[2*base+i]=hval[myslot[c]]; c++; }
    }
    if(t==0) mG[k]=mcnt;
    __syncthreads();
    // union phase: lock-free CAS hooks (id-decreasing => acyclic)
    for(int i=t;i<SCH;i+=1024){
      u32 lw=((u32*)lid16)[base+i];
      u32 sa=lw&0xFFFFu, sb=lw>>16;
      if(sa==sb) continue;
      u32 a=(u32)svroot16[k*MAXSV+sa];
      u32 b=(u32)svroot16[k*MAXSV+sb];
      while(true){
        u32 x=a; while(true){u32 px=ald(&ufG[x]); if(px==x)break; u32 g=ald(&ufG[px]); if(g!=px) ast(&ufG[x],g); x=g;}
        u32 y=b; while(true){u32 py=ald(&ufG[y]); if(py==y)break; u32 g=ald(&ufG[py]); if(g!=py) ast(&ufG[y],g); y=g;}
        if(x==y) break;
        u32 hi=x>y?x:y, lo=x^y^hi;
        if(atomicCAS(&ufG[hi],hi,lo)==hi) break;
        a=hi; b=lo;
      }
    }
    __syncthreads(); __threadfence(); __syncthreads();
    u32 mc=mcnt;
    for(u32 s=t;s<mc;s+=1024){
      u32 r0=(u32)svroot16[k*MAXSV+s];
      u32 x=r0; while(true){u32 px=ald(&ufG[x]); if(px==x)break; u32 g=ald(&ufG[px]); if(g!=px) ast(&ufG[x],g); x=g;}
      svnext16[k*MAXSV+s]=(u16)x;
      if(x!=r0) atomicAdd(&szG[x], (u32)svsize16[k*MAXSV+s]+1u);
    }
    __syncthreads(); __threadfence(); __syncthreads();
  }
}

// ---------------- P2: per-chunk local Kruskal (170 blocks) -------------------
__global__ void __launch_bounds__(64) p2_chunk(
  const u16* __restrict__ lid16,
  const u16* __restrict__ svsize16, const u16* __restrict__ svnext16, const u32* __restrict__ mG,
  u16* __restrict__ outChA, u16* __restrict__ outChB, u16* __restrict__ outSize16, u16* __restrict__ outJ16,
  u32* __restrict__ accCnt, u16* __restrict__ compR16, u16* __restrict__ compTop16, u32* __restrict__ ncomp)
{
  int k = blockIdx.x; int t = threadIdx.x;
  __shared__ u16 uf[MAXSV];
  __shared__ u32 csize[MAXSV];
  __shared__ u16 ctop[MAXSV];
  __shared__ u16 svnl[MAXSV];
  __shared__ u32 cmp_s;
  u32 m = mG[k];
  for(u32 s=t;s<m;s+=64){
    uf[s]=(u16)s;
    csize[s]=(u32)svsize16[k*MAXSV+s]+1u;
    ctop[s]=(u16)s;
    svnl[s]=svnext16[k*MAXSV+s];
  }
  if(t==0) cmp_s=0u;
  __syncthreads();   // svsize16/svnext16[k,*] consumed -> overlay-safe
  if(t==0){
    int base=k*SCH;
    u32 cnt=0;
    for(int j=0;j<SCH;j++){
      u32 lw = ((const u32*)lid16)[base+j];
      u32 la = lw & 0xFFFFu, lb = lw >> 16;
      u32 x=la; while(true){u32 px=uf[x]; if(px==x)break; u32 g=uf[px]; uf[x]=(u16)g; x=g;}
      u32 y=lb; while(true){u32 py=uf[y]; if(py==y)break; u32 g=uf[py]; uf[y]=(u16)g; y=g;}
      if(x==y) continue;
      u32 sa=csize[x], sb=csize[y], ns=sa+sb;
      outChA[base+cnt]=ctop[x];
      outChB[base+cnt]=ctop[y];
      outSize16[base+cnt]=(u16)(ns-1u);
      outJ16[base+cnt]=(u16)j;
      u32 win=(sa>=sb)?x:y, los=x^y^win;
      uf[los]=(u16)win; csize[win]=ns; ctop[win]=(u16)(0x8000u|cnt);
      cnt++;
    }
    accCnt[k]=cnt;
  }
  __syncthreads();
  for(u32 s=t;s<m;s+=64){
    if(uf[s]==(u16)s && (ctop[s]&0x8000u)){
      u32 pos=atomicAdd(&cmp_s,1u);
      compR16[k*MAXSV+pos]=svnl[s];
      compTop16[k*MAXSV+pos]=(u16)(ctop[s]&0x7FFFu);
    }
  }
  __syncthreads();
  if(t==0) ncomp[k]=cmp_s;
}

// ---------------- P3: stitch (1 block x 1024) --------------------------------
__global__ void __launch_bounds__(1024) p3_stitch(
  const u32* __restrict__ accCnt, const u16* __restrict__ outChA, const u16* __restrict__ outChB,
  const u16* __restrict__ outSize16, const u16* __restrict__ outJ16,
  const u16* __restrict__ svroot16,
  const u16* __restrict__ compR16, const u16* __restrict__ compTop16, const u32* __restrict__ ncomp,
  const u32* __restrict__ order, const float* __restrict__ w,
  u16* __restrict__ canonTop16, u32* __restrict__ parent, float* __restrict__ alt, u16* __restrict__ usize16,
  u32* __restrict__ diag)
{
  __shared__ u32 accBase[CCH];
  int t=threadIdx.x;
  if(t==0){ u32 r=0; for(int k=0;k<CCH;k++){ accBase[k]=r; r+=accCnt[k]; } diag[1]=r; }
  __syncthreads();
  for(int idx=t; idx<N_EDGES; idx+=1024){
    int k = idx/SCH; int j = idx - k*SCH;
    if(j < (int)accCnt[k]){
      u32 nid = (u32)L_VERTS + accBase[k] + (u32)j;
      u32 p = (u32)(k*SCH) + (u32)outJ16[idx];
      alt[nid] = w[order[p]];
      usize16[nid] = outSize16[idx];
      u32 cA=outChA[idx]; if(cA & 0x8000u) parent[(u32)L_VERTS+accBase[k]+(cA&0x7FFFu)] = nid;
      u32 cB=outChB[idx]; if(cB & 0x8000u) parent[(u32)L_VERTS+accBase[k]+(cB&0x7FFFu)] = nid;
    }
  }
  __syncthreads();
  for(int k=0;k<CCH;k++){
    u32 ac=accCnt[k];
    for(u32 j=t;j<ac;j+=1024){
      u32 idx=(u32)(k*SCH)+j;
      u32 nid=(u32)L_VERTS+accBase[k]+j;
      u32 cA=outChA[idx];
      if(!(cA&0x8000u)){
        u32 root=(u32)svroot16[k*MAXSV+cA];
        u32 ct=(u32)canonTop16[root];
        parent[(ct==0xFFFFu)?root:((u32)L_VERTS+ct)]=nid;
      }
      u32 cB=outChB[idx];
      if(!(cB&0x8000u)){
        u32 root=(u32)svroot16[k*MAXSV+cB];
        u32 ct=(u32)canonTop16[root];
        parent[(ct==0xFFFFu)?root:((u32)L_VERTS+ct)]=nid;
      }
    }
    __syncthreads();
    u32 nc=ncomp[k];
    for(u32 j=t;j<nc;j+=1024){
      canonTop16[(u32)compR16[k*MAXSV+j]] = (u16)(accBase[k]+compTop16[k*MAXSV+j]);
    }
    __syncthreads();
  }
}

// ---------------- verify (tripwires; removed once stable) --------------------
// diag[0]=flag bits (b0 acc, b1 root, b2 alt, b3 size), diag[1]=accTotal, diag[2]=rootCnt
__global__ void verify_zero(u32* chsum, u32* diag){
  int i=blockIdx.x*blockDim.x+threadIdx.x;
  if(i<L_VERTS) chsum[i]=0u;
  if(i==0){ diag[0]=0u; diag[2]=0u; }
}
__global__ void verify_pass1(const u32* __restrict__ parent, const float* __restrict__ alt,
                             const u16* __restrict__ usize16, u32* chsum, u32* diag){
  int i=blockIdx.x*blockDim.x+threadIdx.x;
  if(i>=N_NODES) return;
  u32 p=parent[i];
  if(p==(u32)i){ atomicAdd(&diag[2],1u); return; }
  u32 sz = (i<L_VERTS)?1u:((u32)usize16[i]+1u);
  atomicAdd(&chsum[p-L_VERTS], sz + (1u<<24));
  if(alt[p] < alt[i]) atomicOr(&diag[0], 4u);
}
__global__ void verify_pass2(const u16* __restrict__ usize16, const u32* chsum, u32* diag){
  int i=blockIdx.x*blockDim.x+threadIdx.x;
  if(i==0){
    if(diag[1]!=(u32)(L_VERTS-1)) atomicOr(&diag[0],1u);
    if(diag[2]!=1u)               atomicOr(&diag[0],2u);
  }
  if(i>=L_VERTS-1) return;   // internal nodes L..L+65534
  u32 n=(u32)L_VERTS+(u32)i;
  u32 expect=((u32)usize16[n]+1u)+(2u<<24);
  if(chsum[i]!=expect) atomicOr(&diag[0],8u);
}
__global__ void fixup(const u32* diag, float* out){
  u32 f=diag[0];
  if(f==0u) return;
  float v = (f&1u)?2.0e6f : (f&2u)?3.0e6f : (f&4u)?4.0e6f : 5.0e6f;
  int i=blockIdx.x*blockDim.x+threadIdx.x;
  if(i<N_NODES) out[i]=v;
}

// ---------------- softarea ----------------
__device__ __forceinline__ float sigmoidf_(float z){ return 1.0f/(1.0f+__expf(-z)); }

// hot nodes (size>=512, provably <=255): pack (hotIdx+1) into parent bits 17..25
__global__ void mark_hot(u16* __restrict__ usize16, u32* __restrict__ parent,
                         u32* __restrict__ hotList, u32* __restrict__ hotCnt, float* __restrict__ out){
  int i=blockIdx.x*blockDim.x+threadIdx.x;
  if(i>=N_NODES) return;
  out[i] = (i<L_VERTS)?0.5f:0.0f;
  if(i<L_VERTS){ usize16[i]=0; }
  else if(usize16[i]>=511u){
    u32 pos=atomicAdd(hotCnt,1u);
    if(pos<256u){ hotList[pos]=(u32)i; parent[i] |= ((pos+1u)<<17); }
  }
}

__global__ void outside_kernel(const u32* __restrict__ parent, const float* __restrict__ alt,
                               const u16* __restrict__ usize16, float* __restrict__ out){
  int n=blockIdx.x*blockDim.x+threadIdx.x;
  if(n>=N_NODES) return;
  float an=alt[n];
  float szc=(float)((u32)usize16[n]+1u);
  float acc=0.f;
  u32 cur=(u32)n;
  u32 p=parent[n]&PMASK;
  while(p!=cur){                      // parents strictly increase -> terminates
    float sza=(float)((u32)usize16[p]+1u);
    acc += (sza-szc)*sigmoidf_(an-alt[p]);
    szc=sza; cur=p; p=parent[p]&PMASK;
  }
  out[n]+=acc;
}

__global__ void inside_kernel(const u32* __restrict__ parent, const float* __restrict__ alt,
                              const u32* __restrict__ hotList, const u32* __restrict__ hotCnt,
                              float* __restrict__ out){
  __shared__ float hacc[256];
  int t=threadIdx.x;
  hacc[t]=0.f;
  __syncthreads();
  int x=blockIdx.x*blockDim.x+t;
  u32 a=parent[x]&PMASK;              // leaf always has a parent
  float b=alt[a];
  while(true){
    u32 pp=parent[a];
    float v=sigmoidf_(alt[a]-b);
    u32 code=pp>>17;
    if(code) atomicAdd(&hacc[code-1u], v);
    else     atomicAdd(&out[a], v);
    u32 na=pp&PMASK;
    if(na==a) break;
    a=na;
  }
  __syncthreads();
  u32 hc=*hotCnt; if(hc>256u) hc=256u;
  for(u32 i=t;i<hc;i+=256){ float v=hacc[i]; if(v!=0.f) atomicAdd(&out[hotList[i]], v); }
}

__global__ void ws_too_small(float* out){
  int i=blockIdx.x*blockDim.x+threadIdx.x;
  if(i<N_NODES) out[i]=1.0e6f;
}

// ---------------- launch ----------------
extern "C" void kernel_launch(void* const* d_in, const int* in_sizes, int n_in,
                              void* d_out, int out_size, void* d_ws, size_t ws_size,
                              hipStream_t stream){
  (void)in_sizes; (void)n_in; (void)out_size;
  const float* w  = (const float*)d_in[0];
  const int* src  = (const int*)d_in[1];
  const int* dst  = (const int*)d_in[2];
  float* out = (float*)d_out;

  char* ws = (char*)d_ws;
  size_t off=0;
  auto alloc=[&](size_t bytes)->void*{ void* p = ws+off; off += (bytes+511)&~(size_t)511; return p; };
  u32* parent   =(u32*)alloc((size_t)N_NODES*4);
  float* alt    =(float*)alloc((size_t)N_NODES*4);
  u16* usize16  =(u16*)alloc(262144);            // u16[N_NODES]; aliases szG=u32[L_VERTS]
  u32* szG      =(u32*)usize16;
  u16* canonTop16=(u16*)alloc((size_t)L_VERTS*2);
  u32* hotList  =(u32*)alloc(256*4);
  u32* hotCnt   =(u32*)alloc(4);
  u32* diag     =(u32*)alloc(512);
  u32* keys0    =(u32*)alloc((size_t)N_EDGES*4); // dead after sort -> outChB16+outSize16
  u32* vals0    =(u32*)alloc((size_t)N_EDGES*4); // sorted order (alive through P3)
  u32* vals1    =(u32*)alloc((size_t)N_EDGES*4); // sort scratch -> lid16
  u32* histG    =(u32*)alloc(256*NB*4);          // dead after sort -> outChA16
  u32* ufG      =(u32*)alloc((size_t)L_VERTS*4); // dead after P1 -> verify chsum
  u16* outJ16   =(u16*)alloc((size_t)N_EDGES*2);
  u16* svroot16 =(u16*)alloc((size_t)CCH*MAXSV*2);
  u16* svsize16 =(u16*)alloc((size_t)CCH*MAXSV*2); // dead after P2 load -> compR16
  u16* svnext16 =(u16*)alloc((size_t)CCH*MAXSV*2); // dead after P2 load -> compTop16
  u32* mG       =(u32*)alloc(CCH*4);
  u32* accCnt   =(u32*)alloc(CCH*4);
  u32* ncomp    =(u32*)alloc(CCH*4);

  if(off > ws_size){
    ws_too_small<<<(N_NODES+255)/256,256,0,stream>>>(out);
    return;
  }

  u16* lid16    =(u16*)vals1;
  u16* outChA16 =(u16*)histG;
  u16* outChB16 =(u16*)keys0;
  u16* outSize16=(u16*)((char*)keys0 + (size_t)N_EDGES*2);
  u16* compR16  =svsize16;
  u16* compTop16=svnext16;
  u32* chsum    =ufG;

  init_keys<<<(N_EDGES+255)/256,256,0,stream>>>(w,keys0,vals0);
  for(int pass=0;pass<4;pass++){
    const u32* iv = (pass&1)?vals1:vals0;
    u32* ov = (pass&1)?vals0:vals1;
    int shift=pass*8;
    radix_hist   <<<NB,TPB,0,stream>>>(iv,keys0,histG,shift);
    radix_scan   <<<1,1024,0,stream>>>(histG);
    radix_scatter<<<NB,TPB,0,stream>>>(iv,keys0,ov,histG,shift);
  }
  init_all<<<(N_NODES+255)/256,256,0,stream>>>(ufG,szG,canonTop16,parent,alt,hotCnt);
  p1_checkpoints<<<1,1024,0,stream>>>(vals0,src,dst,ufG,szG,lid16,svroot16,svsize16,svnext16,mG);
  p2_chunk<<<CCH,64,0,stream>>>(lid16,svsize16,svnext16,mG,
                                outChA16,outChB16,outSize16,outJ16,accCnt,compR16,compTop16,ncomp);
  p3_stitch<<<1,1024,0,stream>>>(accCnt,outChA16,outChB16,outSize16,outJ16,svroot16,
                                 compR16,compTop16,ncomp,vals0,w,canonTop16,parent,alt,usize16,diag);
  verify_zero <<<(L_VERTS+255)/256,256,0,stream>>>(chsum,diag);
  verify_pass1<<<(N_NODES+255)/256,256,0,stream>>>(parent,alt,usize16,chsum,diag);
  verify_pass2<<<(L_VERTS+255)/256,256,0,stream>>>(usize16,chsum,diag);
  mark_hot<<<(N_NODES+255)/256,256,0,stream>>>(usize16,parent,hotList,hotCnt,out);
  outside_kernel<<<(N_NODES+255)/256,256,0,stream>>>(parent,alt,usize16,out);
  inside_kernel<<<L_VERTS/256,256,0,stream>>>(parent,alt,hotList,hotCnt,out);
  fixup<<<(N_NODES+255)/256,256,0,stream>>>(diag,out);
}

// Round 5
// 5311.838 us; speedup vs baseline: 24.7436x; 7.1815x over previous
//
#include <hip/hip_runtime.h>
#include <stdint.h>

typedef unsigned int u32;
typedef unsigned short u16;

#define L_VERTS 65536
#define N_EDGES 130560
#define N_NODES 131071   // 2*L - 1
#define NODEPAD 131072

// chunked-parallel tree build: 170 chunks x 768 edges = 130560
#define CCH 170
#define SCH 768
#define MAXSV 1536

// ---------------- radix sort (stable LSD, index ping-pong, gathered keys) ----
#define NB 255
#define TPB 64
#define IPT 8
#define IPB 512

__global__ void init_keys(const float* __restrict__ w, u32* __restrict__ keys, u32* __restrict__ vals){
  int i = blockIdx.x*blockDim.x + threadIdx.x;
  if(i < N_EDGES){ keys[i] = __float_as_uint(w[i]); vals[i] = (u32)i; } // w>=0 -> uint order == float order
}

__global__ void radix_hist(const u32* __restrict__ idx, const u32* __restrict__ keys,
                           u32* __restrict__ histG, int shift){
  __shared__ u32 h[256];
  for(int i=threadIdx.x;i<256;i+=TPB) h[i]=0;
  __syncthreads();
  int base = blockIdx.x*IPB + threadIdx.x*IPT;
  #pragma unroll
  for(int i=0;i<IPT;i++){
    u32 e = idx[base+i];
    u32 d = (keys[e]>>shift)&255u;
    atomicAdd(&h[d],1u);
  }
  __syncthreads();
  for(int i=threadIdx.x;i<256;i+=TPB) histG[i*NB+blockIdx.x]=h[i];  // digit-major
}

__global__ void radix_scan(u32* histG){
  const int M = 256*NB;
  __shared__ u32 sums[1024];
  int t=threadIdx.x; int s=t*64; u32 acc=0;
  for(int i=0;i<64;i++){int id=s+i; if(id<M) acc+=histG[id];}
  sums[t]=acc; __syncthreads();
  for(int off=1; off<1024; off<<=1){
    u32 v=(t>=off)?sums[t-off]:0u;
    __syncthreads();
    sums[t]+=v;
    __syncthreads();
  }
  u32 run = (t==0)?0u:sums[t-1];
  for(int i=0;i<64;i++){int id=s+i; if(id<M){u32 v=histG[id]; histG[id]=run; run+=v;}}
}

__global__ void radix_scatter(const u32* __restrict__ idxIn, const u32* __restrict__ keys,
                              u32* __restrict__ idxOut, const u32* __restrict__ histG, int shift){
  __shared__ u16 thoff[256][TPB];
  int t=threadIdx.x;
  for(int d=t;d<256;d+=TPB) for(int j=0;j<TPB;j++) thoff[d][j]=0;
  __syncthreads();
  int base = blockIdx.x*IPB + t*IPT;
  u32 myv[IPT]; u32 myd[IPT];
  #pragma unroll
  for(int i=0;i<IPT;i++){
    myv[i]=idxIn[base+i];
    myd[i]=(keys[myv[i]]>>shift)&255u;
    thoff[myd[i]][t]++;
  }
  __syncthreads();
  for(int dd=0;dd<4;dd++){
    int d=t*4+dd; u32 run=0;
    for(int j=0;j<TPB;j++){ u32 v=thoff[d][j]; thoff[d][j]=(u16)run; run+=v; }
  }
  __syncthreads();
  #pragma unroll
  for(int i=0;i<IPT;i++){
    u32 d=myd[i];
    u32 pos = histG[d*NB+blockIdx.x] + (u32)thoff[d][t];
    thoff[d][t]++;                       // stable within thread
    idxOut[pos]=myv[i];
  }
}

// ---------------- init ----------------
__global__ void init_all(u32* ufG,u32* szG,u16* canonTop16,u32* parent,float* alt){
  int i=blockIdx.x*blockDim.x+threadIdx.x;
  if(i<N_NODES){ parent[i]=(u32)i; alt[i]=0.f; }
  if(i<L_VERTS){ ufG[i]=(u32)i; szG[i]=1u; canonTop16[i]=0xFFFFu; }
}

__device__ __forceinline__ u32 ald(u32* p){
  return __hip_atomic_load(p, __ATOMIC_RELAXED, __HIP_MEMORY_SCOPE_AGENT);
}
__device__ __forceinline__ void ast(u32* p, u32 v){
  __hip_atomic_store(p, v, __ATOMIC_RELAXED, __HIP_MEMORY_SCOPE_AGENT);
}

// ---------------- P1: checkpoints + global CC (1 block x 1024) ---------------
__global__ void __launch_bounds__(1024) p1_checkpoints(
    const u32* __restrict__ order, const int* __restrict__ srcv, const int* __restrict__ dstv,
    u32* ufG, u32* szG, u16* lid16, u16* svroot16, u16* svsize16, u16* svnext16, u32* mG)
{
  __shared__ u32 hkey[4096];
  __shared__ u16 hval[4096];
  __shared__ u32 mcnt;
  int t = threadIdx.x;
  for(int k=0;k<CCH;k++){
    for(int i=t;i<4096;i+=1024) hkey[i]=0xFFFFFFFFu;
    if(t==0) mcnt=0u;
    __syncthreads();
    int base = k*SCH;
    u32 myr[2]; int myslot[2]; int myclaim[2]; int mycnt=0;
    for(int i=t;i<2*SCH;i+=1024){
      int p = base + (i>>1);
      u32 e = order[p];
      u32 v = (i&1)? (u32)dstv[e] : (u32)srcv[e];
      u32 x=v;
      while(true){ u32 px=ald(&ufG[x]); if(px==x)break; u32 g=ald(&ufG[px]); if(g!=px) ast(&ufG[x],g); x=g; }
      u32 r=x;
      u32 h=(r*2654435761u)>>20;
      int slot=0; int claim=0;
      while(true){
        u32 old=atomicCAS(&hkey[h],0xFFFFFFFFu,r);
        if(old==0xFFFFFFFFu){slot=(int)h;claim=1;break;}
        if(old==r){slot=(int)h;break;}
        h=(h+1)&4095u;
      }
      myr[mycnt]=r; myslot[mycnt]=slot; myclaim[mycnt]=claim; mycnt++;
    }
    __syncthreads();
    for(int c=0;c<mycnt;c++) if(myclaim[c]){
      u32 id=atomicAdd(&mcnt,1u);
      hval[myslot[c]]=(u16)id;
      svroot16[k*MAXSV+id]=(u16)myr[c];
      svsize16[k*MAXSV+id]=(u16)(ald(&szG[myr[c]])-1u);
    }
    __syncthreads();
    {
      int c=0;
      for(int i=t;i<2*SCH;i+=1024){ lid16[2*base+i]=hval[myslot[c]]; c++; }
    }
    if(t==0) mG[k]=mcnt;
    __syncthreads();
    for(int i=t;i<SCH;i+=1024){
      u32 lw=((u32*)lid16)[base+i];
      u32 sa=lw&0xFFFFu, sb=lw>>16;
      if(sa==sb) continue;
      u32 a=(u32)svroot16[k*MAXSV+sa];
      u32 b=(u32)svroot16[k*MAXSV+sb];
      while(true){
        u32 x=a; while(true){u32 px=ald(&ufG[x]); if(px==x)break; u32 g=ald(&ufG[px]); if(g!=px) ast(&ufG[x],g); x=g;}
        u32 y=b; while(true){u32 py=ald(&ufG[y]); if(py==y)break; u32 g=ald(&ufG[py]); if(g!=py) ast(&ufG[y],g); y=g;}
        if(x==y) break;
        u32 hi=x>y?x:y, lo=x^y^hi;
        if(atomicCAS(&ufG[hi],hi,lo)==hi) break;
        a=hi; b=lo;
      }
    }
    __syncthreads(); __threadfence(); __syncthreads();
    u32 mc=mcnt;
    for(u32 s=t;s<mc;s+=1024){
      u32 r0=(u32)svroot16[k*MAXSV+s];
      u32 x=r0; while(true){u32 px=ald(&ufG[x]); if(px==x)break; u32 g=ald(&ufG[px]); if(g!=px) ast(&ufG[x],g); x=g;}
      svnext16[k*MAXSV+s]=(u16)x;
      if(x!=r0) atomicAdd(&szG[x], (u32)svsize16[k*MAXSV+s]+1u);
    }
    __syncthreads(); __threadfence(); __syncthreads();
  }
}

// ---------------- P2: per-chunk local Kruskal (170 blocks) -------------------
__global__ void __launch_bounds__(64) p2_chunk(
  const u16* __restrict__ lid16,
  const u16* __restrict__ svsize16, const u16* __restrict__ svnext16, const u32* __restrict__ mG,
  u16* __restrict__ outChA, u16* __restrict__ outChB, u16* __restrict__ outSize16, u16* __restrict__ outJ16,
  u32* __restrict__ accCnt, u16* __restrict__ compR16, u16* __restrict__ compTop16, u32* __restrict__ ncomp)
{
  int k = blockIdx.x; int t = threadIdx.x;
  __shared__ u16 uf[MAXSV];
  __shared__ u32 csize[MAXSV];
  __shared__ u16 ctop[MAXSV];
  __shared__ u16 svnl[MAXSV];
  __shared__ u32 cmp_s;
  u32 m = mG[k];
  for(u32 s=t;s<m;s+=64){
    uf[s]=(u16)s;
    csize[s]=(u32)svsize16[k*MAXSV+s]+1u;
    ctop[s]=(u16)s;
    svnl[s]=svnext16[k*MAXSV+s];
  }
  if(t==0) cmp_s=0u;
  __syncthreads();
  if(t==0){
    int base=k*SCH;
    u32 cnt=0;
    for(int j=0;j<SCH;j++){
      u32 lw = ((const u32*)lid16)[base+j];
      u32 la = lw & 0xFFFFu, lb = lw >> 16;
      u32 x=la; while(true){u32 px=uf[x]; if(px==x)break; u32 g=uf[px]; uf[x]=(u16)g; x=g;}
      u32 y=lb; while(true){u32 py=uf[y]; if(py==y)break; u32 g=uf[py]; uf[y]=(u16)g; y=g;}
      if(x==y) continue;
      u32 sa=csize[x], sb=csize[y], ns=sa+sb;
      outChA[base+cnt]=ctop[x];
      outChB[base+cnt]=ctop[y];
      outSize16[base+cnt]=(u16)(ns-1u);
      outJ16[base+cnt]=(u16)j;
      u32 win=(sa>=sb)?x:y, los=x^y^win;
      uf[los]=(u16)win; csize[win]=ns; ctop[win]=(u16)(0x8000u|cnt);
      cnt++;
    }
    accCnt[k]=cnt;
  }
  __syncthreads();
  for(u32 s=t;s<m;s+=64){
    if(uf[s]==(u16)s && (ctop[s]&0x8000u)){
      u32 pos=atomicAdd(&cmp_s,1u);
      compR16[k*MAXSV+pos]=svnl[s];
      compTop16[k*MAXSV+pos]=(u16)(ctop[s]&0x7FFFu);
    }
  }
  __syncthreads();
  if(t==0) ncomp[k]=cmp_s;
}

// ---------------- P3: stitch (1 block x 1024) --------------------------------
__global__ void __launch_bounds__(1024) p3_stitch(
  const u32* __restrict__ accCnt, const u16* __restrict__ outChA, const u16* __restrict__ outChB,
  const u16* __restrict__ outSize16, const u16* __restrict__ outJ16,
  const u16* __restrict__ svroot16,
  const u16* __restrict__ compR16, const u16* __restrict__ compTop16, const u32* __restrict__ ncomp,
  const u32* __restrict__ order, const float* __restrict__ w,
  u16* __restrict__ canonTop16, u32* __restrict__ parent, float* __restrict__ alt, u16* __restrict__ usize16,
  u32* __restrict__ diag)
{
  __shared__ u32 accBase[CCH];
  int t=threadIdx.x;
  if(t==0){ u32 r=0; for(int k=0;k<CCH;k++){ accBase[k]=r; r+=accCnt[k]; } diag[1]=r; }
  __syncthreads();
  for(int idx=t; idx<N_EDGES; idx+=1024){
    int k = idx/SCH; int j = idx - k*SCH;
    if(j < (int)accCnt[k]){
      u32 nid = (u32)L_VERTS + accBase[k] + (u32)j;
      u32 p = (u32)(k*SCH) + (u32)outJ16[idx];
      alt[nid] = w[order[p]];
      usize16[nid] = outSize16[idx];
      u32 cA=outChA[idx]; if(cA & 0x8000u) parent[(u32)L_VERTS+accBase[k]+(cA&0x7FFFu)] = nid;
      u32 cB=outChB[idx]; if(cB & 0x8000u) parent[(u32)L_VERTS+accBase[k]+(cB&0x7FFFu)] = nid;
    }
  }
  __syncthreads();
  for(int k=0;k<CCH;k++){
    u32 ac=accCnt[k];
    for(u32 j=t;j<ac;j+=1024){
      u32 idx=(u32)(k*SCH)+j;
      u32 nid=(u32)L_VERTS+accBase[k]+j;
      u32 cA=outChA[idx];
      if(!(cA&0x8000u)){
        u32 root=(u32)svroot16[k*MAXSV+cA];
        u32 ct=(u32)canonTop16[root];
        parent[(ct==0xFFFFu)?root:((u32)L_VERTS+ct)]=nid;
      }
      u32 cB=outChB[idx];
      if(!(cB&0x8000u)){
        u32 root=(u32)svroot16[k*MAXSV+cB];
        u32 ct=(u32)canonTop16[root];
        parent[(ct==0xFFFFu)?root:((u32)L_VERTS+ct)]=nid;
      }
    }
    __syncthreads();
    u32 nc=ncomp[k];
    for(u32 j=t;j<nc;j+=1024){
      canonTop16[(u32)compR16[k*MAXSV+j]] = (u16)(accBase[k]+compTop16[k*MAXSV+j]);
    }
    __syncthreads();
  }
}

// ---------------- verify tripwires -------------------------------------------
__global__ void verify_zero(u32* chsum, u32* diag){
  int i=blockIdx.x*blockDim.x+threadIdx.x;
  if(i<L_VERTS) chsum[i]=0u;
  if(i==0){ diag[0]=0u; diag[2]=0u; }
}
__global__ void verify_pass1(const u32* __restrict__ parent, const float* __restrict__ alt,
                             const u16* __restrict__ usize16, u32* chsum, u32* diag){
  int i=blockIdx.x*blockDim.x+threadIdx.x;
  if(i>=N_NODES) return;
  u32 p=parent[i];
  if(p==(u32)i){ atomicAdd(&diag[2],1u); return; }
  u32 sz = (i<L_VERTS)?1u:((u32)usize16[i]+1u);
  atomicAdd(&chsum[p-L_VERTS], sz + (1u<<24));
  if(alt[p] < alt[i]) atomicOr(&diag[0], 4u);
}
__global__ void verify_pass2(const u16* __restrict__ usize16, u32* chsum, u32* diag){
  int i=blockIdx.x*blockDim.x+threadIdx.x;
  if(i==0){
    if(diag[1]!=(u32)(L_VERTS-1)) atomicOr(&diag[0],1u);
    if(diag[2]!=1u)               atomicOr(&diag[0],2u);
  }
  if(i<L_VERTS-1){
    u32 n=(u32)L_VERTS+(u32)i;
    u32 expect=((u32)usize16[n]+1u)+(2u<<24);
    if(chsum[i]!=expect) atomicOr(&diag[0],8u);
  }
  if(i<L_VERTS) chsum[i]=0u;   // becomes childCnt (cc) for prep_init
}
__global__ void fixup(const u32* diag, float* out){
  u32 f=diag[0];
  if(f==0u) return;
  float v = (f&1u)?2.0e6f : (f&2u)?3.0e6f : (f&4u)?4.0e6f : 5.0e6f;
  int i=blockIdx.x*blockDim.x+threadIdx.x;
  if(i<N_NODES) out[i]=v;
}

// ---------------- softarea via degree-5 sigmoid poly + DFS intervals ---------
// sigma(u-v) ~ sum_j u^j h_j(v), Taylor deg-5: c=[1/2,1/4,0,-1/48,0,1/480]
__device__ __forceinline__ void hvals3(float v, int j0, float* o){
  float v2=v*v, v3=v2*v, v4=v2*v2, v5=v4*v;
  if(j0==0){
    o[0]=0.5f-0.25f*v+v3*(1.f/48.f)-v5*(1.f/480.f);
    o[1]=0.25f-v2*(1.f/16.f)+v4*(1.f/96.f);
    o[2]=v*(1.f/16.f)-v3*(1.f/48.f);
  }else{
    o[0]=v2*(1.f/48.f)-(1.f/48.f);
    o[1]=-v*(1.f/96.f);
    o[2]=(1.f/480.f);
  }
}

// prep: out init; per-node downward-prefix seeds (leafLo, preOrd) + J=parent
__global__ void prep_init(const u32* __restrict__ parent, const u16* __restrict__ usize16,
                          u32* cc, u32* J0, uint2* A0, float* out){
  int n=blockIdx.x*blockDim.x+threadIdx.x;
  if(n>=N_NODES) return;
  out[n] = (n<L_VERTS)?0.5f:0.0f;
  if(n==N_NODES-1){ J0[n]=(u32)n; A0[n]=make_uint2(0u,0u); return; }  // root
  u32 p=parent[n];
  u32 ord=atomicAdd(&cc[p-L_VERTS],1u);          // 0 or 1: child order (any consistent order valid)
  u32 szP=(u32)usize16[p]+1u;
  u32 szN=(n<L_VERTS)?1u:((u32)usize16[n]+1u);
  u32 sib=szP-szN;                               // sibling subtree leaf count
  A0[n]=make_uint2(ord? sib:0u, 1u + (ord? (2u*sib-1u):0u));
  J0[n]=p;
}

// pointer doubling: A_out[n] = A_in[n] + A_in[J[n]]; J_out[n] = J_in[J_in[n]]
__global__ void double_round(const u32* __restrict__ Jin, const uint2* __restrict__ Ain,
                             u32* __restrict__ Jout, uint2* __restrict__ Aout){
  int n=blockIdx.x*blockDim.x+threadIdx.x;
  if(n>=N_NODES) return;
  u32 j=Jin[n]; uint2 a=Ain[n]; uint2 aj=Ain[j];
  Aout[n]=make_uint2(a.x+aj.x, a.y+aj.y);
  Jout[n]=Jin[j];
}

__global__ void zero_nodeM(float* nodeM){
  int i=blockIdx.x*blockDim.x+threadIdx.x;
  if(i<3*NODEPAD) nodeM[i]=0.f;
}

// leaf x at DFS position accF[x].x: store h_j(b_x), b_x = alt(parent(x))
__global__ void leaf_scatter(const u32* __restrict__ parent, const float* __restrict__ alt,
                             const uint2* __restrict__ accF, float* __restrict__ leafM, int j0){
  int x=blockIdx.x*blockDim.x+threadIdx.x;
  if(x>=L_VERTS) return;
  float b=alt[parent[x]];
  float h[3]; hvals3(b,j0,h);
  u32 pos=accF[x].x;
  leafM[0*L_VERTS+pos]=h[0];
  leafM[1*L_VERTS+pos]=h[1];
  leafM[2*L_VERTS+pos]=h[2];
}

// per non-root node c: term = (size(p)-size(c))*h_j(alt(p)) over pre-order
// interval [pre(c), pre(c)+2*size(c)-1) -> difference array
__global__ void node_scatter(const u32* __restrict__ parent, const float* __restrict__ alt,
                             const u16* __restrict__ usize16, const uint2* __restrict__ accF,
                             float* __restrict__ nodeM, int j0){
  int n=blockIdx.x*blockDim.x+threadIdx.x;
  if(n>=N_NODES-1) return;   // skip root
  u32 p=parent[n];
  u32 szP=(u32)usize16[p]+1u;
  u32 szN=(n<L_VERTS)?1u:((u32)usize16[n]+1u);
  float d=(float)(szP-szN);
  float h[3]; hvals3(alt[p],j0,h);
  u32 q0=accF[n].y;
  u32 q1=q0 + 2u*szN - 1u;   // <= N_NODES fits NODEPAD
  #pragma unroll
  for(int j=0;j<3;j++){
    float tm=d*h[j];
    atomicAdd(&nodeM[j*NODEPAD+q0], tm);
    atomicAdd(&nodeM[j*NODEPAD+q1], -tm);
  }
}

// in-place inclusive block scan (1024 elems/block), emits block sums
__global__ void scanA(float* M, u32 slen, float* bsum){
  int j=blockIdx.y; int b=blockIdx.x; int t=threadIdx.x;
  float* arr = M + (size_t)j*slen;
  __shared__ float s[256];
  u32 base=(u32)b*1024u + (u32)t*4u;
  float v0=arr[base],v1=arr[base+1],v2=arr[base+2],v3=arr[base+3];
  v1+=v0; v2+=v1; v3+=v2;
  s[t]=v3; __syncthreads();
  for(int o=1;o<256;o<<=1){ float x=(t>=o)?s[t-o]:0.f; __syncthreads(); s[t]+=x; __syncthreads(); }
  float pre=(t>0)?s[t-1]:0.f;
  arr[base]=v0+pre; arr[base+1]=v1+pre; arr[base+2]=v2+pre; arr[base+3]=v3+pre;
  if(t==255) bsum[j*gridDim.x+b]=s[255];
}

// exclusive-scan the block sums (3 rows of 64 leaf + 3 rows of 128 node)
__global__ void scanB(float* bsumL, float* bsumN){
  int t=threadIdx.x;
  if(t<3){ float r=0; for(int i=0;i<64;i++){ float v=bsumL[t*64+i]; bsumL[t*64+i]=r; r+=v; } }
  else if(t<6){ int j=t-3; float r=0; for(int i=0;i<128;i++){ float v=bsumN[j*128+i]; bsumN[j*128+i]=r; r+=v; } }
}

// inside(a) += sum_j alt(a)^(j0+j) * (leaf-interval sum of h_j)
__global__ void inside_eval(const uint2* __restrict__ accF, const float* __restrict__ alt,
                            const u16* __restrict__ usize16, const float* __restrict__ leafM,
                            const float* __restrict__ bsumL, float* __restrict__ out, int j0){
  int a=L_VERTS + blockIdx.x*blockDim.x+threadIdx.x;
  if(a>=N_NODES) return;
  u32 lo=accF[a].x;
  u32 hi=lo + (u32)usize16[a] + 1u;
  float u=alt[a];
  float up=1.f; for(int i=0;i<j0;i++) up*=u;
  float acc=0.f;
  #pragma unroll
  for(int j=0;j<3;j++){
    const float* arr=leafM + (size_t)j*L_VERTS;
    const float* bs=bsumL + j*64;
    float Ph = arr[hi-1u] + bs[(hi-1u)>>10];
    float Pl = lo ? (arr[lo-1u] + bs[(lo-1u)>>10]) : 0.f;
    acc += up*(Ph-Pl);
    up*=u;
  }
  out[a]+=acc;
}

// outside(n) += sum_j alt(n)^(j0+j) * T_j(n),  T_j at pre-order pos q
__global__ void outside_eval(const uint2* __restrict__ accF, const float* __restrict__ alt,
                             const float* __restrict__ nodeM, const float* __restrict__ bsumN,
                             float* __restrict__ out, int j0){
  int n=blockIdx.x*blockDim.x+threadIdx.x;
  if(n>=N_NODES) return;
  u32 q=accF[n].y;
  float u=alt[n];
  float up=1.f; for(int i=0;i<j0;i++) up*=u;
  float acc=0.f;
  #pragma unroll
  for(int j=0;j<3;j++){
    float T = nodeM[(size_t)j*NODEPAD+q] + bsumN[j*128 + (q>>10)];
    acc += up*T;
    up*=u;
  }
  out[n]+=acc;
}

__global__ void ws_too_small(float* out){
  int i=blockIdx.x*blockDim.x+threadIdx.x;
  if(i<N_NODES) out[i]=1.0e6f;
}

// ---------------- launch ----------------
extern "C" void kernel_launch(void* const* d_in, const int* in_sizes, int n_in,
                              void* d_out, int out_size, void* d_ws, size_t ws_size,
                              hipStream_t stream){
  (void)in_sizes; (void)n_in; (void)out_size;
  const float* w  = (const float*)d_in[0];
  const int* src  = (const int*)d_in[1];
  const int* dst  = (const int*)d_in[2];
  float* out = (float*)d_out;

  char* ws = (char*)d_ws;
  size_t off=0;
  auto alloc=[&](size_t bytes)->void*{ void* p = ws+off; off += (bytes+511)&~(size_t)511; return p; };
  // persistent
  u32* parent   =(u32*)alloc((size_t)N_NODES*4);
  float* alt    =(float*)alloc((size_t)N_NODES*4);
  u16* usize16  =(u16*)alloc((size_t)N_NODES*2);
  u32* diag     =(u32*)alloc(512);
  float* bsumL  =(float*)alloc(3*64*4);
  float* bsumN  =(float*)alloc(3*128*4);
  size_t scratch0=off;
  // phase A (sort + build) — dead after p3/verify
  u32* keys0    =(u32*)alloc((size_t)N_EDGES*4);
  u32* vals0    =(u32*)alloc((size_t)N_EDGES*4);
  u32* vals1    =(u32*)alloc((size_t)N_EDGES*4);
  u32* histG    =(u32*)alloc(256*NB*4);
  u32* ufG      =(u32*)alloc((size_t)L_VERTS*4);
  u16* canonTop16=(u16*)alloc((size_t)L_VERTS*2);
  u16* outJ16   =(u16*)alloc((size_t)N_EDGES*2);
  u16* svroot16 =(u16*)alloc((size_t)CCH*MAXSV*2);
  u16* svsize16 =(u16*)alloc((size_t)CCH*MAXSV*2);
  u16* svnext16 =(u16*)alloc((size_t)CCH*MAXSV*2);
  u32* mG       =(u32*)alloc(CCH*4);
  u32* accCnt   =(u32*)alloc(CCH*4);
  u32* ncomp    =(u32*)alloc(CCH*4);
  size_t endA=off;
  // phase B (poly softarea) — overlays phase A scratch.
  // NOTE: chsum/cc is allocation #1 and is written during verify (after p3,
  // when all phase-A scratch is dead) — overlay-safe.
  off=scratch0;
  u32* ccChsum  =(u32*)alloc((size_t)L_VERTS*4);     // verify chsum -> childCnt
  u32* J0       =(u32*)alloc((size_t)N_NODES*4);
  u32* J1       =(u32*)alloc((size_t)N_NODES*4);
  uint2* A0     =(uint2*)alloc((size_t)N_NODES*8);
  uint2* A1     =(uint2*)alloc((size_t)N_NODES*8);
  float* leafM  =(float*)alloc((size_t)3*L_VERTS*4);
  float* nodeM  =(float*)alloc((size_t)3*NODEPAD*4);
  size_t endB=off;

  if((endA>ws_size)||(endB>ws_size)){
    ws_too_small<<<(N_NODES+255)/256,256,0,stream>>>(out);
    return;
  }

  u16* lid16    =(u16*)vals1;
  u16* outChA16 =(u16*)histG;
  u16* outChB16 =(u16*)keys0;
  u16* outSize16=(u16*)((char*)keys0 + (size_t)N_EDGES*2);
  u16* compR16  =svsize16;
  u16* compTop16=svnext16;
  u32* chsum    =ccChsum;

  // --- sort ---
  init_keys<<<(N_EDGES+255)/256,256,0,stream>>>(w,keys0,vals0);
  for(int pass=0;pass<4;pass++){
    const u32* iv = (pass&1)?vals1:vals0;
    u32* ov = (pass&1)?vals0:vals1;
    int shift=pass*8;
    radix_hist   <<<NB,TPB,0,stream>>>(iv,keys0,histG,shift);
    radix_scan   <<<1,1024,0,stream>>>(histG);
    radix_scatter<<<NB,TPB,0,stream>>>(iv,keys0,ov,histG,shift);
  }
  // --- tree build ---
  init_all<<<(N_NODES+255)/256,256,0,stream>>>(ufG,(u32*)usize16,canonTop16,parent,alt);
  // (szG aliases usize16 region as u32[L_VERTS]: init_all wrote szG there)
  p1_checkpoints<<<1,1024,0,stream>>>(vals0,src,dst,ufG,(u32*)usize16,lid16,svroot16,svsize16,svnext16,mG);
  p2_chunk<<<CCH,64,0,stream>>>(lid16,svsize16,svnext16,mG,
                                outChA16,outChB16,outSize16,outJ16,accCnt,compR16,compTop16,ncomp);
  p3_stitch<<<1,1024,0,stream>>>(accCnt,outChA16,outChB16,outSize16,outJ16,svroot16,
                                 compR16,compTop16,ncomp,vals0,w,canonTop16,parent,alt,usize16,diag);
  // --- verify (also zeroes cc) ---
  verify_zero <<<(L_VERTS+255)/256,256,0,stream>>>(chsum,diag);
  verify_pass1<<<(N_NODES+255)/256,256,0,stream>>>(parent,alt,usize16,chsum,diag);
  verify_pass2<<<(L_VERTS+255)/256,256,0,stream>>>(usize16,chsum,diag);
  // --- DFS coordinates via pointer doubling (18 rounds, ping-pong) ---
  prep_init<<<(N_NODES+255)/256,256,0,stream>>>(parent,usize16,ccChsum,J0,A0,out);
  for(int r=0;r<18;r++){
    if((r&1)==0) double_round<<<(N_NODES+255)/256,256,0,stream>>>(J0,A0,J1,A1);
    else         double_round<<<(N_NODES+255)/256,256,0,stream>>>(J1,A1,J0,A0);
  }
  const uint2* accF=A0;  // 18 rounds (even) -> final in A0
  // --- two moment batches: j0=0 (h0..h2), j0=3 (h3..h5) ---
  for(int j0=0;j0<=3;j0+=3){
    zero_nodeM<<<(3*NODEPAD+255)/256,256,0,stream>>>(nodeM);
    leaf_scatter<<<(L_VERTS+255)/256,256,0,stream>>>(parent,alt,accF,leafM,j0);
    node_scatter<<<(N_NODES+255)/256,256,0,stream>>>(parent,alt,usize16,accF,nodeM,j0);
    scanA<<<dim3(64,3),256,0,stream>>>(leafM,L_VERTS,bsumL);
    scanA<<<dim3(128,3),256,0,stream>>>(nodeM,NODEPAD,bsumN);
    scanB<<<1,64,0,stream>>>(bsumL,bsumN);
    inside_eval<<<(L_VERTS+255)/256,256,0,stream>>>(accF,alt,usize16,leafM,bsumL,out,j0);
    outside_eval<<<(N_NODES+255)/256,256,0,stream>>>(accF,alt,nodeM,bsumN,out,j0);
  }
  fixup<<<(N_NODES+255)/256,256,0,stream>>>(diag,out);
}

// Round 6
// 4615.203 us; speedup vs baseline: 28.4785x; 1.1509x over previous
//
#include <hip/hip_runtime.h>
#include <stdint.h>

typedef unsigned int u32;
typedef unsigned short u16;

#define L_VERTS 65536
#define N_EDGES 130560
#define N_NODES 131071   // 2*L - 1
#define NODEPAD 131072

// chunked-parallel tree build: 170 chunks x 768 edges = 130560
#define CCH 170
#define SCH 768
#define MAXSV 1536

// ---------------- radix sort (stable LSD, index ping-pong, gathered keys) ----
#define NB 255
#define TPB 64
#define IPT 8
#define IPB 512

__global__ void init_keys(const float* __restrict__ w, u32* __restrict__ keys, u32* __restrict__ vals){
  int i = blockIdx.x*blockDim.x + threadIdx.x;
  if(i < N_EDGES){ keys[i] = __float_as_uint(w[i]); vals[i] = (u32)i; } // w>=0 -> uint order == float order
}

__global__ void radix_hist(const u32* __restrict__ idx, const u32* __restrict__ keys,
                           u32* __restrict__ histG, int shift){
  __shared__ u32 h[256];
  for(int i=threadIdx.x;i<256;i+=TPB) h[i]=0;
  __syncthreads();
  int base = blockIdx.x*IPB + threadIdx.x*IPT;
  #pragma unroll
  for(int i=0;i<IPT;i++){
    u32 e = idx[base+i];
    u32 d = (keys[e]>>shift)&255u;
    atomicAdd(&h[d],1u);
  }
  __syncthreads();
  for(int i=threadIdx.x;i<256;i+=TPB) histG[i*NB+blockIdx.x]=h[i];  // digit-major
}

__global__ void radix_scan(u32* histG){
  const int M = 256*NB;
  __shared__ u32 sums[1024];
  int t=threadIdx.x; int s=t*64; u32 acc=0;
  for(int i=0;i<64;i++){int id=s+i; if(id<M) acc+=histG[id];}
  sums[t]=acc; __syncthreads();
  for(int off=1; off<1024; off<<=1){
    u32 v=(t>=off)?sums[t-off]:0u;
    __syncthreads();
    sums[t]+=v;
    __syncthreads();
  }
  u32 run = (t==0)?0u:sums[t-1];
  for(int i=0;i<64;i++){int id=s+i; if(id<M){u32 v=histG[id]; histG[id]=run; run+=v;}}
}

__global__ void radix_scatter(const u32* __restrict__ idxIn, const u32* __restrict__ keys,
                              u32* __restrict__ idxOut, const u32* __restrict__ histG, int shift){
  __shared__ u16 thoff[256][TPB];
  int t=threadIdx.x;
  for(int d=t;d<256;d+=TPB) for(int j=0;j<TPB;j++) thoff[d][j]=0;
  __syncthreads();
  int base = blockIdx.x*IPB + t*IPT;
  u32 myv[IPT]; u32 myd[IPT];
  #pragma unroll
  for(int i=0;i<IPT;i++){
    myv[i]=idxIn[base+i];
    myd[i]=(keys[myv[i]]>>shift)&255u;
    thoff[myd[i]][t]++;
  }
  __syncthreads();
  for(int dd=0;dd<4;dd++){
    int d=t*4+dd; u32 run=0;
    for(int j=0;j<TPB;j++){ u32 v=thoff[d][j]; thoff[d][j]=(u16)run; run+=v; }
  }
  __syncthreads();
  #pragma unroll
  for(int i=0;i<IPT;i++){
    u32 d=myd[i];
    u32 pos = histG[d*NB+blockIdx.x] + (u32)thoff[d][t];
    thoff[d][t]++;                       // stable within thread
    idxOut[pos]=myv[i];
  }
}

// ---------------- init ----------------
__global__ void init_all(u32* ufG,u32* szG,u16* canonTop16,u32* parent,float* alt){
  int i=blockIdx.x*blockDim.x+threadIdx.x;
  if(i<N_NODES){ parent[i]=(u32)i; alt[i]=0.f; }
  if(i<L_VERTS){ ufG[i]=(u32)i; szG[i]=1u; canonTop16[i]=0xFFFFu; }
}

__device__ __forceinline__ u32 ald(u32* p){
  return __hip_atomic_load(p, __ATOMIC_RELAXED, __HIP_MEMORY_SCOPE_AGENT);
}
__device__ __forceinline__ void ast(u32* p, u32 v){
  __hip_atomic_store(p, v, __ATOMIC_RELAXED, __HIP_MEMORY_SCOPE_AGENT);
}

// ---------------- P1: checkpoints + global CC (1 block x 1024) ---------------
// Slot-space rewrite: global ufG is only touched by (a) endpoint finds w/
// halving + direct compression, (b) one disjoint star-hook store per merged
// root, (c) one size store per component. All unions/aggregation happen on
// compact slot ids in LDS. Rep = largest slot (union-by-size) keeps the giant
// component's root stable -> short global chains.
__global__ void __launch_bounds__(1024) p1_checkpoints(
    const u32* __restrict__ order, const int* __restrict__ srcv, const int* __restrict__ dstv,
    u32* ufG, u32* szG, u16* lid16, u16* svroot16, u16* svsize16, u16* svnext16, u32* mG)
{
  __shared__ u32 hkey[2048];
  __shared__ u16 hval[2048];
  __shared__ u32 suf[MAXSV];
  __shared__ u32 ssz[MAXSV];
  __shared__ u32 compsz[MAXSV];
  __shared__ u32 repkey[MAXSV];
  __shared__ u32 mcnt;
  int t = threadIdx.x;
  for(int k=0;k<CCH;k++){
    for(int i=t;i<2048;i+=1024) hkey[i]=0xFFFFFFFFu;
    if(t==0) mcnt=0u;
    __syncthreads();
    int base = k*SCH;
    u32 myr[2]; int myslot[2]; int myclaim[2]; int mycnt=0;
    for(int i=t;i<2*SCH;i+=1024){
      int p = base + (i>>1);
      u32 e = order[p];
      u32 v = (i&1)? (u32)dstv[e] : (u32)srcv[e];
      u32 x=v;
      while(true){ u32 px=ald(&ufG[x]); if(px==x)break; u32 g=ald(&ufG[px]); if(g!=px) ast(&ufG[x],g); x=g; }
      u32 r=x;
      if(v!=r) ast(&ufG[v],r);        // direct path compression (benign race)
      u32 h=(r*2654435761u)>>21;      // [0,2048)
      int slot=0; int claim=0;
      while(true){
        u32 old=atomicCAS(&hkey[h],0xFFFFFFFFu,r);
        if(old==0xFFFFFFFFu){slot=(int)h;claim=1;break;}
        if(old==r){slot=(int)h;break;}
        h=(h+1)&2047u;
      }
      myr[mycnt]=r; myslot[mycnt]=slot; myclaim[mycnt]=claim; mycnt++;
    }
    __syncthreads();
    for(int c=0;c<mycnt;c++) if(myclaim[c]){
      u32 id=atomicAdd(&mcnt,1u);
      hval[myslot[c]]=(u16)id;
      u32 sz=ald(&szG[myr[c]]);
      svroot16[k*MAXSV+id]=(u16)myr[c];
      svsize16[k*MAXSV+id]=(u16)(sz-1u);
      ssz[id]=sz;
    }
    __syncthreads();
    {
      int c=0;
      for(int i=t;i<2*SCH;i+=1024){ lid16[2*base+i]=hval[myslot[c]]; c++; }
    }
    u32 mc=mcnt;
    if(t==0) mG[k]=mc;
    for(u32 s=t;s<mc;s+=1024){ suf[s]=s; compsz[s]=0u; repkey[s]=0u; }
    __syncthreads();
    // slot unions, all-LDS (min-id CAS hooks => acyclic, terminates)
    for(int i=t;i<SCH;i+=1024){
      u32 lw=((u32*)lid16)[base+i];
      u32 sa=lw&0xFFFFu, sb=lw>>16;
      if(sa==sb) continue;
      while(true){
        u32 x=sa; while(true){u32 p2=suf[x]; if(p2==x)break; u32 g=suf[p2]; if(g!=p2) suf[x]=g; x=g;}
        u32 y=sb; while(true){u32 p2=suf[y]; if(p2==y)break; u32 g=suf[p2]; if(g!=p2) suf[y]=g; y=g;}
        if(x==y) break;
        u32 hi=x>y?x:y, lo=x^y^hi;
        if(atomicCAS(&suf[hi],hi,lo)==hi) break;
        sa=hi; sb=lo;
      }
    }
    __syncthreads();
    // per-component aggregation: total size + rep (max checkpoint size)
    for(u32 s=t;s<mc;s+=1024){
      u32 x=s; while(true){u32 p2=suf[x]; if(p2==x)break; x=p2;}
      suf[s]=x;                                   // values only decrease -> safe
      atomicAdd(&compsz[x], ssz[s]);
      atomicMax(&repkey[x], (ssz[s]<<11) | (2047u - s));   // tie -> smallest slot
    }
    __syncthreads();
    // outputs + disjoint global updates
    for(u32 s=t;s<mc;s+=1024){
      u32 rs=suf[s];
      u32 rep=2047u-(repkey[rs]&2047u);
      u32 w=(u32)svroot16[k*MAXSV+rep];
      svnext16[k*MAXSV+s]=(u16)w;
      u32 myroot=(u32)svroot16[k*MAXSV+s];
      if(myroot!=w) ast(&ufG[myroot],w);          // star hook, one writer per root
      if(s==rep)    ast(&szG[w], compsz[rs]);     // one writer per component
    }
    __syncthreads(); __threadfence(); __syncthreads();
  }
}

// ---------------- P2: per-chunk local Kruskal (170 blocks) -------------------
__global__ void __launch_bounds__(64) p2_chunk(
  const u16* __restrict__ lid16,
  const u16* __restrict__ svsize16, const u16* __restrict__ svnext16, const u32* __restrict__ mG,
  u16* __restrict__ outChA, u16* __restrict__ outChB, u16* __restrict__ outSize16, u16* __restrict__ outJ16,
  u32* __restrict__ accCnt, u16* __restrict__ compR16, u16* __restrict__ compTop16, u32* __restrict__ ncomp)
{
  int k = blockIdx.x; int t = threadIdx.x;
  __shared__ u16 uf[MAXSV];
  __shared__ u32 csize[MAXSV];
  __shared__ u16 ctop[MAXSV];
  __shared__ u16 svnl[MAXSV];
  __shared__ u32 cmp_s;
  u32 m = mG[k];
  for(u32 s=t;s<m;s+=64){
    uf[s]=(u16)s;
    csize[s]=(u32)svsize16[k*MAXSV+s]+1u;
    ctop[s]=(u16)s;
    svnl[s]=svnext16[k*MAXSV+s];
  }
  if(t==0) cmp_s=0u;
  __syncthreads();
  if(t==0){
    int base=k*SCH;
    u32 cnt=0;
    for(int j=0;j<SCH;j++){
      u32 lw = ((const u32*)lid16)[base+j];
      u32 la = lw & 0xFFFFu, lb = lw >> 16;
      u32 x=la; while(true){u32 px=uf[x]; if(px==x)break; u32 g=uf[px]; uf[x]=(u16)g; x=g;}
      u32 y=lb; while(true){u32 py=uf[y]; if(py==y)break; u32 g=uf[py]; uf[y]=(u16)g; y=g;}
      if(x==y) continue;
      u32 sa=csize[x], sb=csize[y], ns=sa+sb;
      outChA[base+cnt]=ctop[x];
      outChB[base+cnt]=ctop[y];
      outSize16[base+cnt]=(u16)(ns-1u);
      outJ16[base+cnt]=(u16)j;
      u32 win=(sa>=sb)?x:y, los=x^y^win;
      uf[los]=(u16)win; csize[win]=ns; ctop[win]=(u16)(0x8000u|cnt);
      cnt++;
    }
    accCnt[k]=cnt;
  }
  __syncthreads();
  for(u32 s=t;s<m;s+=64){
    if(uf[s]==(u16)s && (ctop[s]&0x8000u)){
      u32 pos=atomicAdd(&cmp_s,1u);
      compR16[k*MAXSV+pos]=svnl[s];
      compTop16[k*MAXSV+pos]=(u16)(ctop[s]&0x7FFFu);
    }
  }
  __syncthreads();
  if(t==0) ncomp[k]=cmp_s;
}

// ---------------- P3: stitch (1 block x 1024) --------------------------------
__global__ void __launch_bounds__(1024) p3_stitch(
  const u32* __restrict__ accCnt, const u16* __restrict__ outChA, const u16* __restrict__ outChB,
  const u16* __restrict__ outSize16, const u16* __restrict__ outJ16,
  const u16* __restrict__ svroot16,
  const u16* __restrict__ compR16, const u16* __restrict__ compTop16, const u32* __restrict__ ncomp,
  const u32* __restrict__ order, const float* __restrict__ w,
  u16* __restrict__ canonTop16, u32* __restrict__ parent, float* __restrict__ alt, u16* __restrict__ usize16,
  u32* __restrict__ diag)
{
  __shared__ u32 accBase[CCH];
  int t=threadIdx.x;
  if(t==0){ u32 r=0; for(int k=0;k<CCH;k++){ accBase[k]=r; r+=accCnt[k]; } diag[1]=r; }
  __syncthreads();
  for(int idx=t; idx<N_EDGES; idx+=1024){
    int k = idx/SCH; int j = idx - k*SCH;
    if(j < (int)accCnt[k]){
      u32 nid = (u32)L_VERTS + accBase[k] + (u32)j;
      u32 p = (u32)(k*SCH) + (u32)outJ16[idx];
      alt[nid] = w[order[p]];
      usize16[nid] = outSize16[idx];
      u32 cA=outChA[idx]; if(cA & 0x8000u) parent[(u32)L_VERTS+accBase[k]+(cA&0x7FFFu)] = nid;
      u32 cB=outChB[idx]; if(cB & 0x8000u) parent[(u32)L_VERTS+accBase[k]+(cB&0x7FFFu)] = nid;
    }
  }
  __syncthreads();
  for(int k=0;k<CCH;k++){
    u32 ac=accCnt[k];
    for(u32 j=t;j<ac;j+=1024){
      u32 idx=(u32)(k*SCH)+j;
      u32 nid=(u32)L_VERTS+accBase[k]+j;
      u32 cA=outChA[idx];
      if(!(cA&0x8000u)){
        u32 root=(u32)svroot16[k*MAXSV+cA];
        u32 ct=(u32)canonTop16[root];
        parent[(ct==0xFFFFu)?root:((u32)L_VERTS+ct)]=nid;
      }
      u32 cB=outChB[idx];
      if(!(cB&0x8000u)){
        u32 root=(u32)svroot16[k*MAXSV+cB];
        u32 ct=(u32)canonTop16[root];
        parent[(ct==0xFFFFu)?root:((u32)L_VERTS+ct)]=nid;
      }
    }
    __syncthreads();
    u32 nc=ncomp[k];
    for(u32 j=t;j<nc;j+=1024){
      canonTop16[(u32)compR16[k*MAXSV+j]] = (u16)(accBase[k]+compTop16[k*MAXSV+j]);
    }
    __syncthreads();
  }
}

// ---------------- verify tripwires -------------------------------------------
__global__ void verify_zero(u32* chsum, u32* diag){
  int i=blockIdx.x*blockDim.x+threadIdx.x;
  if(i<L_VERTS) chsum[i]=0u;
  if(i==0){ diag[0]=0u; diag[2]=0u; }
}
__global__ void verify_pass1(const u32* __restrict__ parent, const float* __restrict__ alt,
                             const u16* __restrict__ usize16, u32* chsum, u32* diag){
  int i=blockIdx.x*blockDim.x+threadIdx.x;
  if(i>=N_NODES) return;
  u32 p=parent[i];
  if(p==(u32)i){ atomicAdd(&diag[2],1u); return; }
  u32 sz = (i<L_VERTS)?1u:((u32)usize16[i]+1u);
  atomicAdd(&chsum[p-L_VERTS], sz + (1u<<24));
  if(alt[p] < alt[i]) atomicOr(&diag[0], 4u);
}
__global__ void verify_pass2(const u16* __restrict__ usize16, u32* chsum, u32* diag){
  int i=blockIdx.x*blockDim.x+threadIdx.x;
  if(i==0){
    if(diag[1]!=(u32)(L_VERTS-1)) atomicOr(&diag[0],1u);
    if(diag[2]!=1u)               atomicOr(&diag[0],2u);
  }
  if(i<L_VERTS-1){
    u32 n=(u32)L_VERTS+(u32)i;
    u32 expect=((u32)usize16[n]+1u)+(2u<<24);
    if(chsum[i]!=expect) atomicOr(&diag[0],8u);
  }
  if(i<L_VERTS) chsum[i]=0u;   // becomes childCnt (cc) for prep_init
}
__global__ void fixup(const u32* diag, float* out){
  u32 f=diag[0];
  if(f==0u) return;
  float v = (f&1u)?2.0e6f : (f&2u)?3.0e6f : (f&4u)?4.0e6f : 5.0e6f;
  int i=blockIdx.x*blockDim.x+threadIdx.x;
  if(i<N_NODES) out[i]=v;
}

// ---------------- softarea via degree-5 sigmoid poly + DFS intervals ---------
// sigma(u-v) ~ sum_j u^j h_j(v), Taylor deg-5: c=[1/2,1/4,0,-1/48,0,1/480]
__device__ __forceinline__ void hvals3(float v, int j0, float* o){
  float v2=v*v, v3=v2*v, v4=v2*v2, v5=v4*v;
  if(j0==0){
    o[0]=0.5f-0.25f*v+v3*(1.f/48.f)-v5*(1.f/480.f);
    o[1]=0.25f-v2*(1.f/16.f)+v4*(1.f/96.f);
    o[2]=v*(1.f/16.f)-v3*(1.f/48.f);
  }else{
    o[0]=v2*(1.f/48.f)-(1.f/48.f);
    o[1]=-v*(1.f/96.f);
    o[2]=(1.f/480.f);
  }
}

// prep: out init; per-node downward-prefix seeds (leafLo, preOrd) + J=parent
__global__ void prep_init(const u32* __restrict__ parent, const u16* __restrict__ usize16,
                          u32* cc, u32* J0, uint2* A0, float* out){
  int n=blockIdx.x*blockDim.x+threadIdx.x;
  if(n>=N_NODES) return;
  out[n] = (n<L_VERTS)?0.5f:0.0f;
  if(n==N_NODES-1){ J0[n]=(u32)n; A0[n]=make_uint2(0u,0u); return; }  // root
  u32 p=parent[n];
  u32 ord=atomicAdd(&cc[p-L_VERTS],1u);          // 0 or 1: child order
  u32 szP=(u32)usize16[p]+1u;
  u32 szN=(n<L_VERTS)?1u:((u32)usize16[n]+1u);
  u32 sib=szP-szN;
  A0[n]=make_uint2(ord? sib:0u, 1u + (ord? (2u*sib-1u):0u));
  J0[n]=p;
}

// fused pointer doubling, 2 rounds per launch:
// A2[n] = A[n]+A[J[n]]+A[J2[n]]+A[J[J2[n]]],  J2out[n] = J[J[J2[n]]] where J2=J[J[n]]
__global__ void double_round2(const u32* __restrict__ Jin, const uint2* __restrict__ Ain,
                              u32* __restrict__ Jout, uint2* __restrict__ Aout){
  int n=blockIdx.x*blockDim.x+threadIdx.x;
  if(n>=N_NODES) return;
  u32 j=Jin[n];
  u32 j2=Jin[j];
  u32 j3=Jin[j2];
  uint2 a=Ain[n], aj=Ain[j], b=Ain[j2], bj=Ain[j3];
  Aout[n]=make_uint2(a.x+aj.x+b.x+bj.x, a.y+aj.y+b.y+bj.y);
  Jout[n]=Jin[j3];
}

__global__ void zero_nodeM(float* nodeM){
  int i=blockIdx.x*blockDim.x+threadIdx.x;
  if(i<3*NODEPAD) nodeM[i]=0.f;
}

// leaf x at DFS position accF[x].x: store h_j(b_x), b_x = alt(parent(x))
__global__ void leaf_scatter(const u32* __restrict__ parent, const float* __restrict__ alt,
                             const uint2* __restrict__ accF, float* __restrict__ leafM, int j0){
  int x=blockIdx.x*blockDim.x+threadIdx.x;
  if(x>=L_VERTS) return;
  float b=alt[parent[x]];
  float h[3]; hvals3(b,j0,h);
  u32 pos=accF[x].x;
  leafM[0*L_VERTS+pos]=h[0];
  leafM[1*L_VERTS+pos]=h[1];
  leafM[2*L_VERTS+pos]=h[2];
}

// per non-root node c: term = (size(p)-size(c))*h_j(alt(p)) over pre-order
// interval [pre(c), pre(c)+2*size(c)-1) -> difference array
__global__ void node_scatter(const u32* __restrict__ parent, const float* __restrict__ alt,
                             const u16* __restrict__ usize16, const uint2* __restrict__ accF,
                             float* __restrict__ nodeM, int j0){
  int n=blockIdx.x*blockDim.x+threadIdx.x;
  if(n>=N_NODES-1) return;   // skip root
  u32 p=parent[n];
  u32 szP=(u32)usize16[p]+1u;
  u32 szN=(n<L_VERTS)?1u:((u32)usize16[n]+1u);
  float d=(float)(szP-szN);
  float h[3]; hvals3(alt[p],j0,h);
  u32 q0=accF[n].y;
  u32 q1=q0 + 2u*szN - 1u;
  #pragma unroll
  for(int j=0;j<3;j++){
    float tm=d*h[j];
    atomicAdd(&nodeM[j*NODEPAD+q0], tm);
    atomicAdd(&nodeM[j*NODEPAD+q1], -tm);
  }
}

// in-place inclusive block scan (1024 elems/block), emits block sums
__global__ void scanA(float* M, u32 slen, float* bsum){
  int j=blockIdx.y; int b=blockIdx.x; int t=threadIdx.x;
  float* arr = M + (size_t)j*slen;
  __shared__ float s[256];
  u32 base=(u32)b*1024u + (u32)t*4u;
  float v0=arr[base],v1=arr[base+1],v2=arr[base+2],v3=arr[base+3];
  v1+=v0; v2+=v1; v3+=v2;
  s[t]=v3; __syncthreads();
  for(int o=1;o<256;o<<=1){ float x=(t>=o)?s[t-o]:0.f; __syncthreads(); s[t]+=x; __syncthreads(); }
  float pre=(t>0)?s[t-1]:0.f;
  arr[base]=v0+pre; arr[base+1]=v1+pre; arr[base+2]=v2+pre; arr[base+3]=v3+pre;
  if(t==255) bsum[j*gridDim.x+b]=s[255];
}

// exclusive-scan the block sums (3 rows of 64 leaf + 3 rows of 128 node)
__global__ void scanB(float* bsumL, float* bsumN){
  int t=threadIdx.x;
  if(t<3){ float r=0; for(int i=0;i<64;i++){ float v=bsumL[t*64+i]; bsumL[t*64+i]=r; r+=v; } }
  else if(t<6){ int j=t-3; float r=0; for(int i=0;i<128;i++){ float v=bsumN[j*128+i]; bsumN[j*128+i]=r; r+=v; } }
}

// inside(a) += sum_j alt(a)^(j0+j) * (leaf-interval sum of h_j)
__global__ void inside_eval(const uint2* __restrict__ accF, const float* __restrict__ alt,
                            const u16* __restrict__ usize16, const float* __restrict__ leafM,
                            const float* __restrict__ bsumL, float* __restrict__ out, int j0){
  int a=L_VERTS + blockIdx.x*blockDim.x+threadIdx.x;
  if(a>=N_NODES) return;
  u32 lo=accF[a].x;
  u32 hi=lo + (u32)usize16[a] + 1u;
  float u=alt[a];
  float up=1.f; for(int i=0;i<j0;i++) up*=u;
  float acc=0.f;
  #pragma unroll
  for(int j=0;j<3;j++){
    const float* arr=leafM + (size_t)j*L_VERTS;
    const float* bs=bsumL + j*64;
    float Ph = arr[hi-1u] + bs[(hi-1u)>>10];
    float Pl = lo ? (arr[lo-1u] + bs[(lo-1u)>>10]) : 0.f;
    acc += up*(Ph-Pl);
    up*=u;
  }
  out[a]+=acc;
}

// outside(n) += sum_j alt(n)^(j0+j) * T_j(n),  T_j at pre-order pos q
__global__ void outside_eval(const uint2* __restrict__ accF, const float* __restrict__ alt,
                             const float* __restrict__ nodeM, const float* __restrict__ bsumN,
                             float* __restrict__ out, int j0){
  int n=blockIdx.x*blockDim.x+threadIdx.x;
  if(n>=N_NODES) return;
  u32 q=accF[n].y;
  float u=alt[n];
  float up=1.f; for(int i=0;i<j0;i++) up*=u;
  float acc=0.f;
  #pragma unroll
  for(int j=0;j<3;j++){
    float T = nodeM[(size_t)j*NODEPAD+q] + bsumN[j*128 + (q>>10)];
    acc += up*T;
    up*=u;
  }
  out[n]+=acc;
}

__global__ void ws_too_small(float* out){
  int i=blockIdx.x*blockDim.x+threadIdx.x;
  if(i<N_NODES) out[i]=1.0e6f;
}

// ---------------- launch ----------------
extern "C" void kernel_launch(void* const* d_in, const int* in_sizes, int n_in,
                              void* d_out, int out_size, void* d_ws, size_t ws_size,
                              hipStream_t stream){
  (void)in_sizes; (void)n_in; (void)out_size;
  const float* w  = (const float*)d_in[0];
  const int* src  = (const int*)d_in[1];
  const int* dst  = (const int*)d_in[2];
  float* out = (float*)d_out;

  char* ws = (char*)d_ws;
  size_t off=0;
  auto alloc=[&](size_t bytes)->void*{ void* p = ws+off; off += (bytes+511)&~(size_t)511; return p; };
  // persistent
  u32* parent   =(u32*)alloc((size_t)N_NODES*4);
  float* alt    =(float*)alloc((size_t)N_NODES*4);
  u16* usize16  =(u16*)alloc((size_t)N_NODES*2);
  u32* diag     =(u32*)alloc(512);
  float* bsumL  =(float*)alloc(3*64*4);
  float* bsumN  =(float*)alloc(3*128*4);
  size_t scratch0=off;
  // phase A (sort + build) — dead after p3/verify
  u32* keys0    =(u32*)alloc((size_t)N_EDGES*4);
  u32* vals0    =(u32*)alloc((size_t)N_EDGES*4);
  u32* vals1    =(u32*)alloc((size_t)N_EDGES*4);
  u32* histG    =(u32*)alloc(256*NB*4);
  u32* ufG      =(u32*)alloc((size_t)L_VERTS*4);
  u16* canonTop16=(u16*)alloc((size_t)L_VERTS*2);
  u16* outJ16   =(u16*)alloc((size_t)N_EDGES*2);
  u16* svroot16 =(u16*)alloc((size_t)CCH*MAXSV*2);
  u16* svsize16 =(u16*)alloc((size_t)CCH*MAXSV*2);
  u16* svnext16 =(u16*)alloc((size_t)CCH*MAXSV*2);
  u32* mG       =(u32*)alloc(CCH*4);
  u32* accCnt   =(u32*)alloc(CCH*4);
  u32* ncomp    =(u32*)alloc(CCH*4);
  size_t endA=off;
  // phase B (poly softarea) — overlays phase A scratch
  off=scratch0;
  u32* ccChsum  =(u32*)alloc((size_t)L_VERTS*4);     // verify chsum -> childCnt
  u32* J0       =(u32*)alloc((size_t)N_NODES*4);
  u32* J1       =(u32*)alloc((size_t)N_NODES*4);
  uint2* A0     =(uint2*)alloc((size_t)N_NODES*8);
  uint2* A1     =(uint2*)alloc((size_t)N_NODES*8);
  float* leafM  =(float*)alloc((size_t)3*L_VERTS*4);
  float* nodeM  =(float*)alloc((size_t)3*NODEPAD*4);
  size_t endB=off;

  if((endA>ws_size)||(endB>ws_size)){
    ws_too_small<<<(N_NODES+255)/256,256,0,stream>>>(out);
    return;
  }

  u16* lid16    =(u16*)vals1;
  u16* outChA16 =(u16*)histG;
  u16* outChB16 =(u16*)keys0;
  u16* outSize16=(u16*)((char*)keys0 + (size_t)N_EDGES*2);
  u16* compR16  =svsize16;
  u16* compTop16=svnext16;
  u32* chsum    =ccChsum;

  // --- sort ---
  init_keys<<<(N_EDGES+255)/256,256,0,stream>>>(w,keys0,vals0);
  for(int pass=0;pass<4;pass++){
    const u32* iv = (pass&1)?vals1:vals0;
    u32* ov = (pass&1)?vals0:vals1;
    int shift=pass*8;
    radix_hist   <<<NB,TPB,0,stream>>>(iv,keys0,histG,shift);
    radix_scan   <<<1,1024,0,stream>>>(histG);
    radix_scatter<<<NB,TPB,0,stream>>>(iv,keys0,ov,histG,shift);
  }
  // --- tree build ---
  init_all<<<(N_NODES+255)/256,256,0,stream>>>(ufG,(u32*)usize16,canonTop16,parent,alt);
  p1_checkpoints<<<1,1024,0,stream>>>(vals0,src,dst,ufG,(u32*)usize16,lid16,svroot16,svsize16,svnext16,mG);
  p2_chunk<<<CCH,64,0,stream>>>(lid16,svsize16,svnext16,mG,
                                outChA16,outChB16,outSize16,outJ16,accCnt,compR16,compTop16,ncomp);
  p3_stitch<<<1,1024,0,stream>>>(accCnt,outChA16,outChB16,outSize16,outJ16,svroot16,
                                 compR16,compTop16,ncomp,vals0,w,canonTop16,parent,alt,usize16,diag);
  // --- verify (also zeroes cc) ---
  verify_zero <<<(L_VERTS+255)/256,256,0,stream>>>(chsum,diag);
  verify_pass1<<<(N_NODES+255)/256,256,0,stream>>>(parent,alt,usize16,chsum,diag);
  verify_pass2<<<(L_VERTS+255)/256,256,0,stream>>>(usize16,chsum,diag);
  // --- DFS coordinates via fused pointer doubling (9 launches = 18 rounds) ---
  prep_init<<<(N_NODES+255)/256,256,0,stream>>>(parent,usize16,ccChsum,J0,A0,out);
  for(int r=0;r<9;r++){
    if((r&1)==0) double_round2<<<(N_NODES+255)/256,256,0,stream>>>(J0,A0,J1,A1);
    else         double_round2<<<(N_NODES+255)/256,256,0,stream>>>(J1,A1,J0,A0);
  }
  const uint2* accF=A1;  // 9 launches (odd) -> final in A1
  // --- two moment batches: j0=0 (h0..h2), j0=3 (h3..h5) ---
  for(int j0=0;j0<=3;j0+=3){
    zero_nodeM<<<(3*NODEPAD+255)/256,256,0,stream>>>(nodeM);
    leaf_scatter<<<(L_VERTS+255)/256,256,0,stream>>>(parent,alt,accF,leafM,j0);
    node_scatter<<<(N_NODES+255)/256,256,0,stream>>>(parent,alt,usize16,accF,nodeM,j0);
    scanA<<<dim3(64,3),256,0,stream>>>(leafM,L_VERTS,bsumL);
    scanA<<<dim3(128,3),256,0,stream>>>(nodeM,NODEPAD,bsumN);
    scanB<<<1,64,0,stream>>>(bsumL,bsumN);
    inside_eval<<<(L_VERTS+255)/256,256,0,stream>>>(accF,alt,usize16,leafM,bsumL,out,j0);
    outside_eval<<<(N_NODES+255)/256,256,0,stream>>>(accF,alt,nodeM,bsumN,out,j0);
  }
  fixup<<<(N_NODES+255)/256,256,0,stream>>>(diag,out);
}

// Round 7
// 4313.585 us; speedup vs baseline: 30.4698x; 1.0699x over previous
//
#include <hip/hip_runtime.h>
#include <stdint.h>

typedef unsigned int u32;
typedef unsigned short u16;

#define L_VERTS 65536
#define N_EDGES 130560
#define N_NODES 131071   // 2*L - 1
#define NODEPAD 131072

// chunked-parallel tree build: 85 chunks x 1536 edges = 130560
#define CCH 85
#define SCH 1536
#define MAXSV 3072
#define HSZ 4096

// ---------------- radix sort (stable LSD, index ping-pong, gathered keys) ----
#define NB 255
#define TPB 64
#define IPT 8
#define IPB 512

__global__ void init_keys(const float* __restrict__ w, u32* __restrict__ keys, u32* __restrict__ vals){
  int i = blockIdx.x*blockDim.x + threadIdx.x;
  if(i < N_EDGES){ keys[i] = __float_as_uint(w[i]); vals[i] = (u32)i; } // w>=0 -> uint order == float order
}

__global__ void radix_hist(const u32* __restrict__ idx, const u32* __restrict__ keys,
                           u32* __restrict__ histG, int shift){
  __shared__ u32 h[256];
  for(int i=threadIdx.x;i<256;i+=TPB) h[i]=0;
  __syncthreads();
  int base = blockIdx.x*IPB + threadIdx.x*IPT;
  #pragma unroll
  for(int i=0;i<IPT;i++){
    u32 e = idx[base+i];
    u32 d = (keys[e]>>shift)&255u;
    atomicAdd(&h[d],1u);
  }
  __syncthreads();
  for(int i=threadIdx.x;i<256;i+=TPB) histG[i*NB+blockIdx.x]=h[i];  // digit-major
}

__global__ void radix_scan(u32* histG){
  const int M = 256*NB;
  __shared__ u32 sums[1024];
  int t=threadIdx.x; int s=t*64; u32 acc=0;
  for(int i=0;i<64;i++){int id=s+i; if(id<M) acc+=histG[id];}
  sums[t]=acc; __syncthreads();
  for(int off=1; off<1024; off<<=1){
    u32 v=(t>=off)?sums[t-off]:0u;
    __syncthreads();
    sums[t]+=v;
    __syncthreads();
  }
  u32 run = (t==0)?0u:sums[t-1];
  for(int i=0;i<64;i++){int id=s+i; if(id<M){u32 v=histG[id]; histG[id]=run; run+=v;}}
}

__global__ void radix_scatter(const u32* __restrict__ idxIn, const u32* __restrict__ keys,
                              u32* __restrict__ idxOut, const u32* __restrict__ histG, int shift){
  __shared__ u16 thoff[256][TPB];
  int t=threadIdx.x;
  for(int d=t;d<256;d+=TPB) for(int j=0;j<TPB;j++) thoff[d][j]=0;
  __syncthreads();
  int base = blockIdx.x*IPB + t*IPT;
  u32 myv[IPT]; u32 myd[IPT];
  #pragma unroll
  for(int i=0;i<IPT;i++){
    myv[i]=idxIn[base+i];
    myd[i]=(keys[myv[i]]>>shift)&255u;
    thoff[myd[i]][t]++;
  }
  __syncthreads();
  for(int dd=0;dd<4;dd++){
    int d=t*4+dd; u32 run=0;
    for(int j=0;j<TPB;j++){ u32 v=thoff[d][j]; thoff[d][j]=(u16)run; run+=v; }
  }
  __syncthreads();
  #pragma unroll
  for(int i=0;i<IPT;i++){
    u32 d=myd[i];
    u32 pos = histG[d*NB+blockIdx.x] + (u32)thoff[d][t];
    thoff[d][t]++;                       // stable within thread
    idxOut[pos]=myv[i];
  }
}

// ---------------- init ----------------
__global__ void init_all(u32* ufG,u32* szG,u16* canonTop16,u32* parent,float* alt){
  int i=blockIdx.x*blockDim.x+threadIdx.x;
  if(i<N_NODES){ parent[i]=(u32)i; alt[i]=0.f; }
  if(i<L_VERTS){ ufG[i]=(u32)i; szG[i]=1u; canonTop16[i]=0xFFFFu; }
}

__device__ __forceinline__ u32 ald(u32* p){
  return __hip_atomic_load(p, __ATOMIC_RELAXED, __HIP_MEMORY_SCOPE_AGENT);
}
__device__ __forceinline__ void ast(u32* p, u32 v){
  __hip_atomic_store(p, v, __ATOMIC_RELAXED, __HIP_MEMORY_SCOPE_AGENT);
}

// ---------------- P1: checkpoints + global CC (1 block x 1024) ---------------
// Slot-space unions in LDS; global ufG touched only by endpoint finds (+direct
// compression), one star-hook store per merged root, one size store per
// component. Slot-id assignment fused into the find/claim phase (one fewer
// barrier). Rep = largest-size slot keeps giant root stable.
__global__ void __launch_bounds__(1024) p1_checkpoints(
    const u32* __restrict__ order, const int* __restrict__ srcv, const int* __restrict__ dstv,
    u32* ufG, u32* szG, u16* lid16, u16* svroot16, u16* svsize16, u16* svnext16, u32* mG)
{
  __shared__ u32 hkey[HSZ];
  __shared__ u16 hval[HSZ];
  __shared__ u32 suf[MAXSV];
  __shared__ u32 ssz[MAXSV];
  __shared__ u32 compsz[MAXSV];
  __shared__ u32 repkey[MAXSV];
  __shared__ u32 mcnt;
  int t = threadIdx.x;
  for(int k=0;k<CCH;k++){
    for(int i=t;i<HSZ;i+=1024) hkey[i]=0xFFFFFFFFu;
    if(t==0) mcnt=0u;
    __syncthreads();
    int base = k*SCH;
    int myslot[3]; int mycnt=0;
    for(int i=t;i<2*SCH;i+=1024){
      int p = base + (i>>1);
      u32 e = order[p];
      u32 v = (i&1)? (u32)dstv[e] : (u32)srcv[e];
      u32 x=v;
      while(true){ u32 px=ald(&ufG[x]); if(px==x)break; u32 g=ald(&ufG[px]); if(g!=px) ast(&ufG[x],g); x=g; }
      u32 r=x;
      if(v!=r) ast(&ufG[v],r);        // direct path compression (benign race)
      u32 h=(r*2654435761u)>>20;      // [0,4096)
      int slot=0;
      while(true){
        u32 old=atomicCAS(&hkey[h],0xFFFFFFFFu,r);
        if(old==0xFFFFFFFFu){
          slot=(int)h;
          u32 id=atomicAdd(&mcnt,1u);   // claim: assign compact id now
          hval[h]=(u16)id;
          u32 sz=ald(&szG[r]);
          svroot16[k*MAXSV+id]=(u16)r;
          svsize16[k*MAXSV+id]=(u16)(sz-1u);
          ssz[id]=sz;
          break;
        }
        if(old==r){slot=(int)h;break;}
        h=(h+1)&(HSZ-1u);
      }
      myslot[mycnt]=slot; mycnt++;
    }
    __syncthreads();
    {
      int c=0;
      for(int i=t;i<2*SCH;i+=1024){ lid16[2*base+i]=hval[myslot[c]]; c++; }
    }
    u32 mc=mcnt;
    if(t==0) mG[k]=mc;
    for(u32 s=t;s<mc;s+=1024){ suf[s]=s; compsz[s]=0u; repkey[s]=0u; }
    __syncthreads();
    // slot unions, all-LDS (min-id CAS hooks => acyclic, terminates)
    for(int i=t;i<SCH;i+=1024){
      u32 lw=((u32*)lid16)[base+i];
      u32 sa=lw&0xFFFFu, sb=lw>>16;
      if(sa==sb) continue;
      while(true){
        u32 x=sa; while(true){u32 p2=suf[x]; if(p2==x)break; u32 g=suf[p2]; if(g!=p2) suf[x]=g; x=g;}
        u32 y=sb; while(true){u32 p2=suf[y]; if(p2==y)break; u32 g=suf[p2]; if(g!=p2) suf[y]=g; y=g;}
        if(x==y) break;
        u32 hi=x>y?x:y, lo=x^y^hi;
        if(atomicCAS(&suf[hi],hi,lo)==hi) break;
        sa=hi; sb=lo;
      }
    }
    __syncthreads();
    // per-component aggregation: total size + rep (max checkpoint size)
    for(u32 s=t;s<mc;s+=1024){
      u32 x=s; while(true){u32 p2=suf[x]; if(p2==x)break; x=p2;}
      suf[s]=x;                                   // values only decrease -> safe
      atomicAdd(&compsz[x], ssz[s]);
      atomicMax(&repkey[x], (ssz[s]<<12) | (4095u - s));   // tie -> smallest slot
    }
    __syncthreads();
    // outputs + disjoint global updates
    for(u32 s=t;s<mc;s+=1024){
      u32 rs=suf[s];
      u32 rep=4095u-(repkey[rs]&4095u);
      u32 w=(u32)svroot16[k*MAXSV+rep];
      svnext16[k*MAXSV+s]=(u16)w;
      u32 myroot=(u32)svroot16[k*MAXSV+s];
      if(myroot!=w) ast(&ufG[myroot],w);          // star hook, one writer per root
      if(s==rep)    ast(&szG[w], compsz[rs]);     // one writer per component
    }
    __syncthreads(); __threadfence(); __syncthreads();
  }
}

// ---------------- P2: per-chunk local Kruskal (85 blocks) --------------------
__global__ void __launch_bounds__(64) p2_chunk(
  const u16* __restrict__ lid16,
  const u16* __restrict__ svsize16, const u16* __restrict__ svnext16, const u32* __restrict__ mG,
  u16* __restrict__ outChA, u16* __restrict__ outChB, u16* __restrict__ outSize16, u16* __restrict__ outJ16,
  u32* __restrict__ accCnt, u16* __restrict__ compR16, u16* __restrict__ compTop16, u32* __restrict__ ncomp)
{
  int k = blockIdx.x; int t = threadIdx.x;
  __shared__ u16 uf[MAXSV];
  __shared__ u32 csize[MAXSV];
  __shared__ u16 ctop[MAXSV];
  __shared__ u16 svnl[MAXSV];
  __shared__ u32 cmp_s;
  u32 m = mG[k];
  for(u32 s=t;s<m;s+=64){
    uf[s]=(u16)s;
    csize[s]=(u32)svsize16[k*MAXSV+s]+1u;
    ctop[s]=(u16)s;
    svnl[s]=svnext16[k*MAXSV+s];
  }
  if(t==0) cmp_s=0u;
  __syncthreads();
  if(t==0){
    int base=k*SCH;
    u32 cnt=0;
    for(int j=0;j<SCH;j++){
      u32 lw = ((const u32*)lid16)[base+j];
      u32 la = lw & 0xFFFFu, lb = lw >> 16;
      u32 x=la; while(true){u32 px=uf[x]; if(px==x)break; u32 g=uf[px]; uf[x]=(u16)g; x=g;}
      u32 y=lb; while(true){u32 py=uf[y]; if(py==y)break; u32 g=uf[py]; uf[y]=(u16)g; y=g;}
      if(x==y) continue;
      u32 sa=csize[x], sb=csize[y], ns=sa+sb;
      outChA[base+cnt]=ctop[x];
      outChB[base+cnt]=ctop[y];
      outSize16[base+cnt]=(u16)(ns-1u);
      outJ16[base+cnt]=(u16)j;
      u32 win=(sa>=sb)?x:y, los=x^y^win;
      uf[los]=(u16)win; csize[win]=ns; ctop[win]=(u16)(0x8000u|cnt);
      cnt++;
    }
    accCnt[k]=cnt;
  }
  __syncthreads();
  for(u32 s=t;s<m;s+=64){
    if(uf[s]==(u16)s && (ctop[s]&0x8000u)){
      u32 pos=atomicAdd(&cmp_s,1u);
      compR16[k*MAXSV+pos]=svnl[s];
      compTop16[k*MAXSV+pos]=(u16)(ctop[s]&0x7FFFu);
    }
  }
  __syncthreads();
  if(t==0) ncomp[k]=cmp_s;
}

// ---------------- P3: stitch (1 block x 1024) --------------------------------
__global__ void __launch_bounds__(1024) p3_stitch(
  const u32* __restrict__ accCnt, const u16* __restrict__ outChA, const u16* __restrict__ outChB,
  const u16* __restrict__ outSize16, const u16* __restrict__ outJ16,
  const u16* __restrict__ svroot16,
  const u16* __restrict__ compR16, const u16* __restrict__ compTop16, const u32* __restrict__ ncomp,
  const u32* __restrict__ order, const float* __restrict__ w,
  u16* __restrict__ canonTop16, u32* __restrict__ parent, float* __restrict__ alt, u16* __restrict__ usize16,
  u32* __restrict__ diag)
{
  __shared__ u32 accBase[CCH];
  int t=threadIdx.x;
  if(t==0){ u32 r=0; for(int k=0;k<CCH;k++){ accBase[k]=r; r+=accCnt[k]; } diag[1]=r; }
  __syncthreads();
  for(int idx=t; idx<N_EDGES; idx+=1024){
    int k = idx/SCH; int j = idx - k*SCH;
    if(j < (int)accCnt[k]){
      u32 nid = (u32)L_VERTS + accBase[k] + (u32)j;
      u32 p = (u32)(k*SCH) + (u32)outJ16[idx];
      alt[nid] = w[order[p]];
      usize16[nid] = outSize16[idx];
      u32 cA=outChA[idx]; if(cA & 0x8000u) parent[(u32)L_VERTS+accBase[k]+(cA&0x7FFFu)] = nid;
      u32 cB=outChB[idx]; if(cB & 0x8000u) parent[(u32)L_VERTS+accBase[k]+(cB&0x7FFFu)] = nid;
    }
  }
  __syncthreads();
  for(int k=0;k<CCH;k++){
    u32 ac=accCnt[k];
    for(u32 j=t;j<ac;j+=1024){
      u32 idx=(u32)(k*SCH)+j;
      u32 nid=(u32)L_VERTS+accBase[k]+j;
      u32 cA=outChA[idx];
      if(!(cA&0x8000u)){
        u32 root=(u32)svroot16[k*MAXSV+cA];
        u32 ct=(u32)canonTop16[root];
        parent[(ct==0xFFFFu)?root:((u32)L_VERTS+ct)]=nid;
      }
      u32 cB=outChB[idx];
      if(!(cB&0x8000u)){
        u32 root=(u32)svroot16[k*MAXSV+cB];
        u32 ct=(u32)canonTop16[root];
        parent[(ct==0xFFFFu)?root:((u32)L_VERTS+ct)]=nid;
      }
    }
    __syncthreads();
    u32 nc=ncomp[k];
    for(u32 j=t;j<nc;j+=1024){
      canonTop16[(u32)compR16[k*MAXSV+j]] = (u16)(accBase[k]+compTop16[k*MAXSV+j]);
    }
    __syncthreads();
  }
}

// ---------------- verify tripwires -------------------------------------------
__global__ void verify_zero(u32* chsum, u32* diag){
  int i=blockIdx.x*blockDim.x+threadIdx.x;
  if(i<L_VERTS) chsum[i]=0u;
  if(i==0){ diag[0]=0u; diag[2]=0u; }
}
__global__ void verify_pass1(const u32* __restrict__ parent, const float* __restrict__ alt,
                             const u16* __restrict__ usize16, u32* chsum, u32* diag){
  int i=blockIdx.x*blockDim.x+threadIdx.x;
  if(i>=N_NODES) return;
  u32 p=parent[i];
  if(p==(u32)i){ atomicAdd(&diag[2],1u); return; }
  u32 sz = (i<L_VERTS)?1u:((u32)usize16[i]+1u);
  atomicAdd(&chsum[p-L_VERTS], sz + (1u<<24));
  if(alt[p] < alt[i]) atomicOr(&diag[0], 4u);
}
__global__ void verify_pass2(const u16* __restrict__ usize16, u32* chsum, u32* diag){
  int i=blockIdx.x*blockDim.x+threadIdx.x;
  if(i==0){
    if(diag[1]!=(u32)(L_VERTS-1)) atomicOr(&diag[0],1u);
    if(diag[2]!=1u)               atomicOr(&diag[0],2u);
  }
  if(i<L_VERTS-1){
    u32 n=(u32)L_VERTS+(u32)i;
    u32 expect=((u32)usize16[n]+1u)+(2u<<24);
    if(chsum[i]!=expect) atomicOr(&diag[0],8u);
  }
  if(i<L_VERTS) chsum[i]=0u;   // becomes childCnt (cc) for prep_init
}
__global__ void fixup(const u32* diag, float* out){
  u32 f=diag[0];
  if(f==0u) return;
  float v = (f&1u)?2.0e6f : (f&2u)?3.0e6f : (f&4u)?4.0e6f : 5.0e6f;
  int i=blockIdx.x*blockDim.x+threadIdx.x;
  if(i<N_NODES) out[i]=v;
}

// ---------------- softarea via degree-5 sigmoid poly + DFS intervals ---------
// sigma(u-v) ~ sum_j u^j h_j(v), Taylor deg-5: c=[1/2,1/4,0,-1/48,0,1/480]
__device__ __forceinline__ void hvals3(float v, int j0, float* o){
  float v2=v*v, v3=v2*v, v4=v2*v2, v5=v4*v;
  if(j0==0){
    o[0]=0.5f-0.25f*v+v3*(1.f/48.f)-v5*(1.f/480.f);
    o[1]=0.25f-v2*(1.f/16.f)+v4*(1.f/96.f);
    o[2]=v*(1.f/16.f)-v3*(1.f/48.f);
  }else{
    o[0]=v2*(1.f/48.f)-(1.f/48.f);
    o[1]=-v*(1.f/96.f);
    o[2]=(1.f/480.f);
  }
}

// prep: out init; per-node downward-prefix seeds (leafLo, preOrd) + J=parent
__global__ void prep_init(const u32* __restrict__ parent, const u16* __restrict__ usize16,
                          u32* cc, u32* J0, uint2* A0, float* out){
  int n=blockIdx.x*blockDim.x+threadIdx.x;
  if(n>=N_NODES) return;
  out[n] = (n<L_VERTS)?0.5f:0.0f;
  if(n==N_NODES-1){ J0[n]=(u32)n; A0[n]=make_uint2(0u,0u); return; }  // root
  u32 p=parent[n];
  u32 ord=atomicAdd(&cc[p-L_VERTS],1u);          // 0 or 1: child order
  u32 szP=(u32)usize16[p]+1u;
  u32 szN=(n<L_VERTS)?1u:((u32)usize16[n]+1u);
  u32 sib=szP-szN;
  A0[n]=make_uint2(ord? sib:0u, 1u + (ord? (2u*sib-1u):0u));
  J0[n]=p;
}

// fused pointer doubling, 2 rounds per launch
__global__ void double_round2(const u32* __restrict__ Jin, const uint2* __restrict__ Ain,
                              u32* __restrict__ Jout, uint2* __restrict__ Aout){
  int n=blockIdx.x*blockDim.x+threadIdx.x;
  if(n>=N_NODES) return;
  u32 j=Jin[n];
  u32 j2=Jin[j];
  u32 j3=Jin[j2];
  uint2 a=Ain[n], aj=Ain[j], b=Ain[j2], bj=Ain[j3];
  Aout[n]=make_uint2(a.x+aj.x+b.x+bj.x, a.y+aj.y+b.y+bj.y);
  Jout[n]=Jin[j3];
}

__global__ void zero_nodeM(float* nodeM){
  int i=blockIdx.x*blockDim.x+threadIdx.x;
  if(i<3*NODEPAD) nodeM[i]=0.f;
}

// leaf x at DFS position accF[x].x: store h_j(b_x), b_x = alt(parent(x))
__global__ void leaf_scatter(const u32* __restrict__ parent, const float* __restrict__ alt,
                             const uint2* __restrict__ accF, float* __restrict__ leafM, int j0){
  int x=blockIdx.x*blockDim.x+threadIdx.x;
  if(x>=L_VERTS) return;
  float b=alt[parent[x]];
  float h[3]; hvals3(b,j0,h);
  u32 pos=accF[x].x;
  leafM[0*L_VERTS+pos]=h[0];
  leafM[1*L_VERTS+pos]=h[1];
  leafM[2*L_VERTS+pos]=h[2];
}

// per non-root node c: term = (size(p)-size(c))*h_j(alt(p)) over pre-order
// interval [pre(c), pre(c)+2*size(c)-1) -> difference array
__global__ void node_scatter(const u32* __restrict__ parent, const float* __restrict__ alt,
                             const u16* __restrict__ usize16, const uint2* __restrict__ accF,
                             float* __restrict__ nodeM, int j0){
  int n=blockIdx.x*blockDim.x+threadIdx.x;
  if(n>=N_NODES-1) return;   // skip root
  u32 p=parent[n];
  u32 szP=(u32)usize16[p]+1u;
  u32 szN=(n<L_VERTS)?1u:((u32)usize16[n]+1u);
  float d=(float)(szP-szN);
  float h[3]; hvals3(alt[p],j0,h);
  u32 q0=accF[n].y;
  u32 q1=q0 + 2u*szN - 1u;
  #pragma unroll
  for(int j=0;j<3;j++){
    float tm=d*h[j];
    atomicAdd(&nodeM[j*NODEPAD+q0], tm);
    atomicAdd(&nodeM[j*NODEPAD+q1], -tm);
  }
}

// in-place inclusive block scan (1024 elems/block), emits block sums
__global__ void scanA(float* M, u32 slen, float* bsum){
  int j=blockIdx.y; int b=blockIdx.x; int t=threadIdx.x;
  float* arr = M + (size_t)j*slen;
  __shared__ float s[256];
  u32 base=(u32)b*1024u + (u32)t*4u;
  float v0=arr[base],v1=arr[base+1],v2=arr[base+2],v3=arr[base+3];
  v1+=v0; v2+=v1; v3+=v2;
  s[t]=v3; __syncthreads();
  for(int o=1;o<256;o<<=1){ float x=(t>=o)?s[t-o]:0.f; __syncthreads(); s[t]+=x; __syncthreads(); }
  float pre=(t>0)?s[t-1]:0.f;
  arr[base]=v0+pre; arr[base+1]=v1+pre; arr[base+2]=v2+pre; arr[base+3]=v3+pre;
  if(t==255) bsum[j*gridDim.x+b]=s[255];
}

// exclusive-scan the block sums (3 rows of 64 leaf + 3 rows of 128 node)
__global__ void scanB(float* bsumL, float* bsumN){
  int t=threadIdx.x;
  if(t<3){ float r=0; for(int i=0;i<64;i++){ float v=bsumL[t*64+i]; bsumL[t*64+i]=r; r+=v; } }
  else if(t<6){ int j=t-3; float r=0; for(int i=0;i<128;i++){ float v=bsumN[j*128+i]; bsumN[j*128+i]=r; r+=v; } }
}

// inside(a) += sum_j alt(a)^(j0+j) * (leaf-interval sum of h_j)
__global__ void inside_eval(const uint2* __restrict__ accF, const float* __restrict__ alt,
                            const u16* __restrict__ usize16, const float* __restrict__ leafM,
                            const float* __restrict__ bsumL, float* __restrict__ out, int j0){
  int a=L_VERTS + blockIdx.x*blockDim.x+threadIdx.x;
  if(a>=N_NODES) return;
  u32 lo=accF[a].x;
  u32 hi=lo + (u32)usize16[a] + 1u;
  float u=alt[a];
  float up=1.f; for(int i=0;i<j0;i++) up*=u;
  float acc=0.f;
  #pragma unroll
  for(int j=0;j<3;j++){
    const float* arr=leafM + (size_t)j*L_VERTS;
    const float* bs=bsumL + j*64;
    float Ph = arr[hi-1u] + bs[(hi-1u)>>10];
    float Pl = lo ? (arr[lo-1u] + bs[(lo-1u)>>10]) : 0.f;
    acc += up*(Ph-Pl);
    up*=u;
  }
  out[a]+=acc;
}

// outside(n) += sum_j alt(n)^(j0+j) * T_j(n),  T_j at pre-order pos q
__global__ void outside_eval(const uint2* __restrict__ accF, const float* __restrict__ alt,
                             const float* __restrict__ nodeM, const float* __restrict__ bsumN,
                             float* __restrict__ out, int j0){
  int n=blockIdx.x*blockDim.x+threadIdx.x;
  if(n>=N_NODES) return;
  u32 q=accF[n].y;
  float u=alt[n];
  float up=1.f; for(int i=0;i<j0;i++) up*=u;
  float acc=0.f;
  #pragma unroll
  for(int j=0;j<3;j++){
    float T = nodeM[(size_t)j*NODEPAD+q] + bsumN[j*128 + (q>>10)];
    acc += up*T;
    up*=u;
  }
  out[n]+=acc;
}

__global__ void ws_too_small(float* out){
  int i=blockIdx.x*blockDim.x+threadIdx.x;
  if(i<N_NODES) out[i]=1.0e6f;
}

// ---------------- launch ----------------
extern "C" void kernel_launch(void* const* d_in, const int* in_sizes, int n_in,
                              void* d_out, int out_size, void* d_ws, size_t ws_size,
                              hipStream_t stream){
  (void)in_sizes; (void)n_in; (void)out_size;
  const float* w  = (const float*)d_in[0];
  const int* src  = (const int*)d_in[1];
  const int* dst  = (const int*)d_in[2];
  float* out = (float*)d_out;

  char* ws = (char*)d_ws;
  size_t off=0;
  auto alloc=[&](size_t bytes)->void*{ void* p = ws+off; off += (bytes+511)&~(size_t)511; return p; };
  // persistent
  u32* parent   =(u32*)alloc((size_t)N_NODES*4);
  float* alt    =(float*)alloc((size_t)N_NODES*4);
  u16* usize16  =(u16*)alloc((size_t)N_NODES*2);
  u32* diag     =(u32*)alloc(512);
  float* bsumL  =(float*)alloc(3*64*4);
  float* bsumN  =(float*)alloc(3*128*4);
  size_t scratch0=off;
  // phase A (sort + build) — dead after p3/verify
  u32* keys0    =(u32*)alloc((size_t)N_EDGES*4);
  u32* vals0    =(u32*)alloc((size_t)N_EDGES*4);
  u32* vals1    =(u32*)alloc((size_t)N_EDGES*4);
  u32* histG    =(u32*)alloc(256*NB*4);
  u32* ufG      =(u32*)alloc((size_t)L_VERTS*4);
  u16* canonTop16=(u16*)alloc((size_t)L_VERTS*2);
  u16* outJ16   =(u16*)alloc((size_t)N_EDGES*2);
  u16* svroot16 =(u16*)alloc((size_t)CCH*MAXSV*2);
  u16* svsize16 =(u16*)alloc((size_t)CCH*MAXSV*2);
  u16* svnext16 =(u16*)alloc((size_t)CCH*MAXSV*2);
  u32* mG       =(u32*)alloc(CCH*4);
  u32* accCnt   =(u32*)alloc(CCH*4);
  u32* ncomp    =(u32*)alloc(CCH*4);
  size_t endA=off;
  // phase B (poly softarea) — overlays phase A scratch
  off=scratch0;
  u32* ccChsum  =(u32*)alloc((size_t)L_VERTS*4);     // verify chsum -> childCnt
  u32* J0       =(u32*)alloc((size_t)N_NODES*4);
  u32* J1       =(u32*)alloc((size_t)N_NODES*4);
  uint2* A0     =(uint2*)alloc((size_t)N_NODES*8);
  uint2* A1     =(uint2*)alloc((size_t)N_NODES*8);
  float* leafM  =(float*)alloc((size_t)3*L_VERTS*4);
  float* nodeM  =(float*)alloc((size_t)3*NODEPAD*4);
  size_t endB=off;

  if((endA>ws_size)||(endB>ws_size)){
    ws_too_small<<<(N_NODES+255)/256,256,0,stream>>>(out);
    return;
  }

  u16* lid16    =(u16*)vals1;
  u16* outChA16 =(u16*)histG;
  u16* outChB16 =(u16*)keys0;
  u16* outSize16=(u16*)((char*)keys0 + (size_t)N_EDGES*2);
  u16* compR16  =svsize16;
  u16* compTop16=svnext16;
  u32* chsum    =ccChsum;

  // --- sort ---
  init_keys<<<(N_EDGES+255)/256,256,0,stream>>>(w,keys0,vals0);
  for(int pass=0;pass<4;pass++){
    const u32* iv = (pass&1)?vals1:vals0;
    u32* ov = (pass&1)?vals0:vals1;
    int shift=pass*8;
    radix_hist   <<<NB,TPB,0,stream>>>(iv,keys0,histG,shift);
    radix_scan   <<<1,1024,0,stream>>>(histG);
    radix_scatter<<<NB,TPB,0,stream>>>(iv,keys0,ov,histG,shift);
  }
  // --- tree build ---
  init_all<<<(N_NODES+255)/256,256,0,stream>>>(ufG,(u32*)usize16,canonTop16,parent,alt);
  p1_checkpoints<<<1,1024,0,stream>>>(vals0,src,dst,ufG,(u32*)usize16,lid16,svroot16,svsize16,svnext16,mG);
  p2_chunk<<<CCH,64,0,stream>>>(lid16,svsize16,svnext16,mG,
                                outChA16,outChB16,outSize16,outJ16,accCnt,compR16,compTop16,ncomp);
  p3_stitch<<<1,1024,0,stream>>>(accCnt,outChA16,outChB16,outSize16,outJ16,svroot16,
                                 compR16,compTop16,ncomp,vals0,w,canonTop16,parent,alt,usize16,diag);
  // --- verify (also zeroes cc) ---
  verify_zero <<<(L_VERTS+255)/256,256,0,stream>>>(chsum,diag);
  verify_pass1<<<(N_NODES+255)/256,256,0,stream>>>(parent,alt,usize16,chsum,diag);
  verify_pass2<<<(L_VERTS+255)/256,256,0,stream>>>(usize16,chsum,diag);
  // --- DFS coordinates via fused pointer doubling (9 launches = 18 rounds) ---
  prep_init<<<(N_NODES+255)/256,256,0,stream>>>(parent,usize16,ccChsum,J0,A0,out);
  for(int r=0;r<9;r++){
    if((r&1)==0) double_round2<<<(N_NODES+255)/256,256,0,stream>>>(J0,A0,J1,A1);
    else         double_round2<<<(N_NODES+255)/256,256,0,stream>>>(J1,A1,J0,A0);
  }
  const uint2* accF=A1;  // 9 launches (odd) -> final in A1
  // --- two moment batches: j0=0 (h0..h2), j0=3 (h3..h5) ---
  for(int j0=0;j0<=3;j0+=3){
    zero_nodeM<<<(3*NODEPAD+255)/256,256,0,stream>>>(nodeM);
    leaf_scatter<<<(L_VERTS+255)/256,256,0,stream>>>(parent,alt,accF,leafM,j0);
    node_scatter<<<(N_NODES+255)/256,256,0,stream>>>(parent,alt,usize16,accF,nodeM,j0);
    scanA<<<dim3(64,3),256,0,stream>>>(leafM,L_VERTS,bsumL);
    scanA<<<dim3(128,3),256,0,stream>>>(nodeM,NODEPAD,bsumN);
    scanB<<<1,64,0,stream>>>(bsumL,bsumN);
    inside_eval<<<(L_VERTS+255)/256,256,0,stream>>>(accF,alt,usize16,leafM,bsumL,out,j0);
    outside_eval<<<(N_NODES+255)/256,256,0,stream>>>(accF,alt,nodeM,bsumN,out,j0);
  }
  fixup<<<(N_NODES+255)/256,256,0,stream>>>(diag,out);
}

// Round 8
// 3214.528 us; speedup vs baseline: 40.8875x; 1.3419x over previous
//
#include <hip/hip_runtime.h>
#include <stdint.h>

typedef unsigned int u32;
typedef unsigned short u16;

#define L_VERTS 65536
#define N_EDGES 130560
#define N_NODES 131071   // 2*L - 1
#define NODEPAD 131072

// chunked-parallel tree build: 170 chunks x 768 edges = 130560
#define CCH 170
#define SCH 768
#define MAXSV 1536
#define HSZ 2048

// ---------------- radix sort (stable LSD, index ping-pong, gathered keys) ----
#define NB 255
#define TPB 64
#define IPT 8
#define IPB 512

__global__ void init_keys(const float* __restrict__ w, u32* __restrict__ keys, u32* __restrict__ vals){
  int i = blockIdx.x*blockDim.x + threadIdx.x;
  if(i < N_EDGES){ keys[i] = __float_as_uint(w[i]); vals[i] = (u32)i; } // w>=0 -> uint order == float order
}

__global__ void radix_hist(const u32* __restrict__ idx, const u32* __restrict__ keys,
                           u32* __restrict__ histG, int shift){
  __shared__ u32 h[256];
  for(int i=threadIdx.x;i<256;i+=TPB) h[i]=0;
  __syncthreads();
  int base = blockIdx.x*IPB + threadIdx.x*IPT;
  #pragma unroll
  for(int i=0;i<IPT;i++){
    u32 e = idx[base+i];
    u32 d = (keys[e]>>shift)&255u;
    atomicAdd(&h[d],1u);
  }
  __syncthreads();
  for(int i=threadIdx.x;i<256;i+=TPB) histG[i*NB+blockIdx.x]=h[i];  // digit-major
}

__global__ void radix_scan(u32* histG){
  const int M = 256*NB;
  __shared__ u32 sums[1024];
  int t=threadIdx.x; int s=t*64; u32 acc=0;
  for(int i=0;i<64;i++){int id=s+i; if(id<M) acc+=histG[id];}
  sums[t]=acc; __syncthreads();
  for(int off=1; off<1024; off<<=1){
    u32 v=(t>=off)?sums[t-off]:0u;
    __syncthreads();
    sums[t]+=v;
    __syncthreads();
  }
  u32 run = (t==0)?0u:sums[t-1];
  for(int i=0;i<64;i++){int id=s+i; if(id<M){u32 v=histG[id]; histG[id]=run; run+=v;}}
}

__global__ void radix_scatter(const u32* __restrict__ idxIn, const u32* __restrict__ keys,
                              u32* __restrict__ idxOut, const u32* __restrict__ histG, int shift){
  __shared__ u16 thoff[256][TPB];
  int t=threadIdx.x;
  for(int d=t;d<256;d+=TPB) for(int j=0;j<TPB;j++) thoff[d][j]=0;
  __syncthreads();
  int base = blockIdx.x*IPB + t*IPT;
  u32 myv[IPT]; u32 myd[IPT];
  #pragma unroll
  for(int i=0;i<IPT;i++){
    myv[i]=idxIn[base+i];
    myd[i]=(keys[myv[i]]>>shift)&255u;
    thoff[myd[i]][t]++;
  }
  __syncthreads();
  for(int dd=0;dd<4;dd++){
    int d=t*4+dd; u32 run=0;
    for(int j=0;j<TPB;j++){ u32 v=thoff[d][j]; thoff[d][j]=(u16)run; run+=v; }
  }
  __syncthreads();
  #pragma unroll
  for(int i=0;i<IPT;i++){
    u32 d=myd[i];
    u32 pos = histG[d*NB+blockIdx.x] + (u32)thoff[d][t];
    thoff[d][t]++;                       // stable within thread
    idxOut[pos]=myv[i];
  }
}

// epair[p] = (dst<<16)|src for sorted position p — removes the order->src/dst
// dependent gather chain from p1's critical path (coalesced stream instead)
__global__ void build_epair(const u32* __restrict__ order, const int* __restrict__ srcv,
                            const int* __restrict__ dstv, u32* __restrict__ epair){
  int p=blockIdx.x*blockDim.x+threadIdx.x;
  if(p>=N_EDGES) return;
  u32 e=order[p];
  epair[p]=((u32)dstv[e]<<16)|(u32)srcv[e];
}

// ---------------- init ----------------
__global__ void init_all(u32* szG,u16* canonTop16,u32* parent,float* alt){
  int i=blockIdx.x*blockDim.x+threadIdx.x;
  if(i<N_NODES){ parent[i]=(u32)i; alt[i]=0.f; }
  if(i<L_VERTS){ szG[i]=1u; canonTop16[i]=0xFFFFu; }
}

__device__ __forceinline__ u32 ald(u32* p){
  return __hip_atomic_load(p, __ATOMIC_RELAXED, __HIP_MEMORY_SCOPE_AGENT);
}
__device__ __forceinline__ void ast(u32* p, u32 v){
  __hip_atomic_store(p, v, __ATOMIC_RELAXED, __HIP_MEMORY_SCOPE_AGENT);
}

// ---------------- P1: checkpoints + global CC (1 block x 1024) ---------------
// Whole-graph union-find lives in LDS (u16[65536] = 128 KB): find hops are
// ~120-cyc LDS chases, not ~300-900-cyc global. Global traffic per edge is one
// coalesced epair load. szG (u32, aliases usize16) stays global: read once per
// slot (claim), written once per component. hval aliases repkey (barrier-
// separated lifetimes) to fit the 160 KB/CU LDS budget (~154 KB total).
__global__ void __launch_bounds__(1024,1) p1_checkpoints(
    const u32* __restrict__ epair,
    u32* szG, u16* lid16, u16* svroot16, u16* svsize16, u16* svnext16, u32* mG)
{
  __shared__ u16 ufL[L_VERTS];     // 128 KB
  __shared__ u32 hkey[HSZ];        // 8 KB
  __shared__ u32 sufL[MAXSV];      // 6 KB
  __shared__ u32 compsz[MAXSV];    // 6 KB
  __shared__ u32 repkey[MAXSV];    // 6 KB; aliased as hval u16[HSZ] in claim phase
  __shared__ u32 mcnt;
  u16* hval=(u16*)repkey;
  int t = threadIdx.x;
  for(int i=t;i<L_VERTS/2;i+=1024) ((u32*)ufL)[i]=((2u*(u32)i+1u)<<16)|(2u*(u32)i); // ufL[v]=v
  for(int k=0;k<CCH;k++){
    for(int i=t;i<HSZ;i+=1024) hkey[i]=0xFFFFFFFFu;
    if(t==0) mcnt=0u;
    __syncthreads();
    int base = k*SCH;
    int myslot[2]; int mycnt=0;
    for(int i=t;i<2*SCH;i+=1024){
      u32 pr = epair[base+(i>>1)];
      u32 v = (i&1)? (pr>>16) : (pr&0xFFFFu);
      u32 x=v;
      while(true){ u32 px=ufL[x]; if(px==x)break; u32 g=ufL[px]; if(g!=px) ufL[x]=(u16)g; x=g; }
      u32 r=x;
      if(v!=r) ufL[v]=(u16)r;       // direct compression (benign race; no hooks this phase)
      u32 h=(r*2654435761u)>>21;    // [0,2048)
      int slot;
      while(true){
        u32 old=atomicCAS(&hkey[h],0xFFFFFFFFu,r);
        if(old==0xFFFFFFFFu){
          slot=(int)h;
          u32 id=atomicAdd(&mcnt,1u);   // claim: assign compact id
          hval[h]=(u16)id;
          u32 sz=ald(&szG[r]);
          svroot16[k*MAXSV+id]=(u16)r;
          svsize16[k*MAXSV+id]=(u16)(sz-1u);
          break;
        }
        if(old==r){slot=(int)h;break;}
        h=(h+1)&(HSZ-1u);
      }
      myslot[mycnt++]=slot;
    }
    __syncthreads();
    {
      int c=0;
      for(int i=t;i<2*SCH;i+=1024){ lid16[2*base+i]=hval[myslot[c]]; c++; }
    }
    u32 mc=mcnt;
    if(t==0) mG[k]=mc;
    __syncthreads();                 // hval reads complete before repkey reuse
    for(u32 s=t;s<mc;s+=1024){ sufL[s]=s; compsz[s]=0u; repkey[s]=0u; }
    __syncthreads();
    // slot unions, all-LDS (min-id CAS hooks => acyclic, terminates)
    for(int i=t;i<SCH;i+=1024){
      u32 lw=((u32*)lid16)[base+i];
      u32 sa=lw&0xFFFFu, sb=lw>>16;
      if(sa==sb) continue;
      while(true){
        u32 x=sa; while(true){u32 p2=sufL[x]; if(p2==x)break; u32 g=sufL[p2]; if(g!=p2) sufL[x]=g; x=g;}
        u32 y=sb; while(true){u32 p2=sufL[y]; if(p2==y)break; u32 g=sufL[p2]; if(g!=p2) sufL[y]=g; y=g;}
        if(x==y) break;
        u32 hi=x>y?x:y, lo=x^y^hi;
        if(atomicCAS(&sufL[hi],hi,lo)==hi) break;
        sa=hi; sb=lo;
      }
    }
    __syncthreads();
    // per-component aggregation: total size + rep (max checkpoint size)
    for(u32 s=t;s<mc;s+=1024){
      u32 x=s; while(true){u32 p2=sufL[x]; if(p2==x)break; x=p2;}
      sufL[s]=x;                                  // values only decrease -> safe
      u32 sz=(u32)svsize16[k*MAXSV+s]+1u;
      atomicAdd(&compsz[x], sz);
      atomicMax(&repkey[x], (sz<<11) | (2047u-s));  // tie -> smallest slot
    }
    __syncthreads();
    // outputs + star hooks (rep = largest component root stays stable)
    for(u32 s=t;s<mc;s+=1024){
      u32 rs=sufL[s];
      u32 rep=2047u-(repkey[rs]&2047u);
      u32 wv=(u32)svroot16[k*MAXSV+rep];
      svnext16[k*MAXSV+s]=(u16)wv;
      u32 myroot=(u32)svroot16[k*MAXSV+s];
      if(myroot!=wv) ufL[myroot]=(u16)wv;         // star hook, one writer per root
      if(s==rep)     ast(&szG[wv], compsz[rs]);   // one writer per component
    }
    __syncthreads();
  }
}

// ---------------- P2: per-chunk local Kruskal (170 blocks) -------------------
__global__ void __launch_bounds__(64) p2_chunk(
  const u16* __restrict__ lid16,
  const u16* __restrict__ svsize16, const u16* __restrict__ svnext16, const u32* __restrict__ mG,
  u16* __restrict__ outChA, u16* __restrict__ outChB, u16* __restrict__ outSize16, u16* __restrict__ outJ16,
  u32* __restrict__ accCnt, u16* __restrict__ compR16, u16* __restrict__ compTop16, u32* __restrict__ ncomp)
{
  int k = blockIdx.x; int t = threadIdx.x;
  __shared__ u16 uf[MAXSV];
  __shared__ u32 csize[MAXSV];
  __shared__ u16 ctop[MAXSV];
  __shared__ u16 svnl[MAXSV];
  __shared__ u32 cmp_s;
  u32 m = mG[k];
  for(u32 s=t;s<m;s+=64){
    uf[s]=(u16)s;
    csize[s]=(u32)svsize16[k*MAXSV+s]+1u;
    ctop[s]=(u16)s;
    svnl[s]=svnext16[k*MAXSV+s];
  }
  if(t==0) cmp_s=0u;
  __syncthreads();
  if(t==0){
    int base=k*SCH;
    u32 cnt=0;
    for(int j=0;j<SCH;j++){
      u32 lw = ((const u32*)lid16)[base+j];
      u32 la = lw & 0xFFFFu, lb = lw >> 16;
      u32 x=la; while(true){u32 px=uf[x]; if(px==x)break; u32 g=uf[px]; uf[x]=(u16)g; x=g;}
      u32 y=lb; while(true){u32 py=uf[y]; if(py==y)break; u32 g=uf[py]; uf[y]=(u16)g; y=g;}
      if(x==y) continue;
      u32 sa=csize[x], sb=csize[y], ns=sa+sb;
      outChA[base+cnt]=ctop[x];
      outChB[base+cnt]=ctop[y];
      outSize16[base+cnt]=(u16)(ns-1u);
      outJ16[base+cnt]=(u16)j;
      u32 win=(sa>=sb)?x:y, los=x^y^win;
      uf[los]=(u16)win; csize[win]=ns; ctop[win]=(u16)(0x8000u|cnt);
      cnt++;
    }
    accCnt[k]=cnt;
  }
  __syncthreads();
  for(u32 s=t;s<m;s+=64){
    if(uf[s]==(u16)s && (ctop[s]&0x8000u)){
      u32 pos=atomicAdd(&cmp_s,1u);
      compR16[k*MAXSV+pos]=svnl[s];
      compTop16[k*MAXSV+pos]=(u16)(ctop[s]&0x7FFFu);
    }
  }
  __syncthreads();
  if(t==0) ncomp[k]=cmp_s;
}

// ---------------- P3: stitch (1 block x 1024) --------------------------------
__global__ void __launch_bounds__(1024) p3_stitch(
  const u32* __restrict__ accCnt, const u16* __restrict__ outChA, const u16* __restrict__ outChB,
  const u16* __restrict__ outSize16, const u16* __restrict__ outJ16,
  const u16* __restrict__ svroot16,
  const u16* __restrict__ compR16, const u16* __restrict__ compTop16, const u32* __restrict__ ncomp,
  const u32* __restrict__ order, const float* __restrict__ w,
  u16* __restrict__ canonTop16, u32* __restrict__ parent, float* __restrict__ alt, u16* __restrict__ usize16,
  u32* __restrict__ diag)
{
  __shared__ u32 accBase[CCH];
  int t=threadIdx.x;
  if(t==0){ u32 r=0; for(int k=0;k<CCH;k++){ accBase[k]=r; r+=accCnt[k]; } diag[1]=r; }
  __syncthreads();
  for(int idx=t; idx<N_EDGES; idx+=1024){
    int k = idx/SCH; int j = idx - k*SCH;
    if(j < (int)accCnt[k]){
      u32 nid = (u32)L_VERTS + accBase[k] + (u32)j;
      u32 p = (u32)(k*SCH) + (u32)outJ16[idx];
      alt[nid] = w[order[p]];
      usize16[nid] = outSize16[idx];
      u32 cA=outChA[idx]; if(cA & 0x8000u) parent[(u32)L_VERTS+accBase[k]+(cA&0x7FFFu)] = nid;
      u32 cB=outChB[idx]; if(cB & 0x8000u) parent[(u32)L_VERTS+accBase[k]+(cB&0x7FFFu)] = nid;
    }
  }
  __syncthreads();
  for(int k=0;k<CCH;k++){
    u32 ac=accCnt[k];
    for(u32 j=t;j<ac;j+=1024){
      u32 idx=(u32)(k*SCH)+j;
      u32 nid=(u32)L_VERTS+accBase[k]+j;
      u32 cA=outChA[idx];
      if(!(cA&0x8000u)){
        u32 root=(u32)svroot16[k*MAXSV+cA];
        u32 ct=(u32)canonTop16[root];
        parent[(ct==0xFFFFu)?root:((u32)L_VERTS+ct)]=nid;
      }
      u32 cB=outChB[idx];
      if(!(cB&0x8000u)){
        u32 root=(u32)svroot16[k*MAXSV+cB];
        u32 ct=(u32)canonTop16[root];
        parent[(ct==0xFFFFu)?root:((u32)L_VERTS+ct)]=nid;
      }
    }
    __syncthreads();
    u32 nc=ncomp[k];
    for(u32 j=t;j<nc;j+=1024){
      canonTop16[(u32)compR16[k*MAXSV+j]] = (u16)(accBase[k]+compTop16[k*MAXSV+j]);
    }
    __syncthreads();
  }
}

// ---------------- verify tripwires -------------------------------------------
__global__ void verify_zero(u32* chsum, u32* diag){
  int i=blockIdx.x*blockDim.x+threadIdx.x;
  if(i<L_VERTS) chsum[i]=0u;
  if(i==0){ diag[0]=0u; diag[2]=0u; }
}
__global__ void verify_pass1(const u32* __restrict__ parent, const float* __restrict__ alt,
                             const u16* __restrict__ usize16, u32* chsum, u32* diag){
  int i=blockIdx.x*blockDim.x+threadIdx.x;
  if(i>=N_NODES) return;
  u32 p=parent[i];
  if(p==(u32)i){ atomicAdd(&diag[2],1u); return; }
  u32 sz = (i<L_VERTS)?1u:((u32)usize16[i]+1u);
  atomicAdd(&chsum[p-L_VERTS], sz + (1u<<24));
  if(alt[p] < alt[i]) atomicOr(&diag[0], 4u);
}
__global__ void verify_pass2(const u16* __restrict__ usize16, u32* chsum, u32* diag){
  int i=blockIdx.x*blockDim.x+threadIdx.x;
  if(i==0){
    if(diag[1]!=(u32)(L_VERTS-1)) atomicOr(&diag[0],1u);
    if(diag[2]!=1u)               atomicOr(&diag[0],2u);
  }
  if(i<L_VERTS-1){
    u32 n=(u32)L_VERTS+(u32)i;
    u32 expect=((u32)usize16[n]+1u)+(2u<<24);
    if(chsum[i]!=expect) atomicOr(&diag[0],8u);
  }
  if(i<L_VERTS) chsum[i]=0u;   // becomes childCnt (cc) for prep_init
}
__global__ void fixup(const u32* diag, float* out){
  u32 f=diag[0];
  if(f==0u) return;
  float v = (f&1u)?2.0e6f : (f&2u)?3.0e6f : (f&4u)?4.0e6f : 5.0e6f;
  int i=blockIdx.x*blockDim.x+threadIdx.x;
  if(i<N_NODES) out[i]=v;
}

// ---------------- softarea via degree-5 sigmoid poly + DFS intervals ---------
__device__ __forceinline__ void hvals3(float v, int j0, float* o){
  float v2=v*v, v3=v2*v, v4=v2*v2, v5=v4*v;
  if(j0==0){
    o[0]=0.5f-0.25f*v+v3*(1.f/48.f)-v5*(1.f/480.f);
    o[1]=0.25f-v2*(1.f/16.f)+v4*(1.f/96.f);
    o[2]=v*(1.f/16.f)-v3*(1.f/48.f);
  }else{
    o[0]=v2*(1.f/48.f)-(1.f/48.f);
    o[1]=-v*(1.f/96.f);
    o[2]=(1.f/480.f);
  }
}

__global__ void prep_init(const u32* __restrict__ parent, const u16* __restrict__ usize16,
                          u32* cc, u32* J0, uint2* A0, float* out){
  int n=blockIdx.x*blockDim.x+threadIdx.x;
  if(n>=N_NODES) return;
  out[n] = (n<L_VERTS)?0.5f:0.0f;
  if(n==N_NODES-1){ J0[n]=(u32)n; A0[n]=make_uint2(0u,0u); return; }  // root
  u32 p=parent[n];
  u32 ord=atomicAdd(&cc[p-L_VERTS],1u);          // 0 or 1: child order
  u32 szP=(u32)usize16[p]+1u;
  u32 szN=(n<L_VERTS)?1u:((u32)usize16[n]+1u);
  u32 sib=szP-szN;
  A0[n]=make_uint2(ord? sib:0u, 1u + (ord? (2u*sib-1u):0u));
  J0[n]=p;
}

// fused pointer doubling, 2 rounds per launch
__global__ void double_round2(const u32* __restrict__ Jin, const uint2* __restrict__ Ain,
                              u32* __restrict__ Jout, uint2* __restrict__ Aout){
  int n=blockIdx.x*blockDim.x+threadIdx.x;
  if(n>=N_NODES) return;
  u32 j=Jin[n];
  u32 j2=Jin[j];
  u32 j3=Jin[j2];
  uint2 a=Ain[n], aj=Ain[j], b=Ain[j2], bj=Ain[j3];
  Aout[n]=make_uint2(a.x+aj.x+b.x+bj.x, a.y+aj.y+b.y+bj.y);
  Jout[n]=Jin[j3];
}

__global__ void zero_nodeM(float* nodeM){
  int i=blockIdx.x*blockDim.x+threadIdx.x;
  if(i<3*NODEPAD) nodeM[i]=0.f;
}

__global__ void leaf_scatter(const u32* __restrict__ parent, const float* __restrict__ alt,
                             const uint2* __restrict__ accF, float* __restrict__ leafM, int j0){
  int x=blockIdx.x*blockDim.x+threadIdx.x;
  if(x>=L_VERTS) return;
  float b=alt[parent[x]];
  float h[3]; hvals3(b,j0,h);
  u32 pos=accF[x].x;
  leafM[0*L_VERTS+pos]=h[0];
  leafM[1*L_VERTS+pos]=h[1];
  leafM[2*L_VERTS+pos]=h[2];
}

__global__ void node_scatter(const u32* __restrict__ parent, const float* __restrict__ alt,
                             const u16* __restrict__ usize16, const uint2* __restrict__ accF,
                             float* __restrict__ nodeM, int j0){
  int n=blockIdx.x*blockDim.x+threadIdx.x;
  if(n>=N_NODES-1) return;   // skip root
  u32 p=parent[n];
  u32 szP=(u32)usize16[p]+1u;
  u32 szN=(n<L_VERTS)?1u:((u32)usize16[n]+1u);
  float d=(float)(szP-szN);
  float h[3]; hvals3(alt[p],j0,h);
  u32 q0=accF[n].y;
  u32 q1=q0 + 2u*szN - 1u;
  #pragma unroll
  for(int j=0;j<3;j++){
    float tm=d*h[j];
    atomicAdd(&nodeM[j*NODEPAD+q0], tm);
    atomicAdd(&nodeM[j*NODEPAD+q1], -tm);
  }
}

__global__ void scanA(float* M, u32 slen, float* bsum){
  int j=blockIdx.y; int b=blockIdx.x; int t=threadIdx.x;
  float* arr = M + (size_t)j*slen;
  __shared__ float s[256];
  u32 base=(u32)b*1024u + (u32)t*4u;
  float v0=arr[base],v1=arr[base+1],v2=arr[base+2],v3=arr[base+3];
  v1+=v0; v2+=v1; v3+=v2;
  s[t]=v3; __syncthreads();
  for(int o=1;o<256;o<<=1){ float x=(t>=o)?s[t-o]:0.f; __syncthreads(); s[t]+=x; __syncthreads(); }
  float pre=(t>0)?s[t-1]:0.f;
  arr[base]=v0+pre; arr[base+1]=v1+pre; arr[base+2]=v2+pre; arr[base+3]=v3+pre;
  if(t==255) bsum[j*gridDim.x+b]=s[255];
}

__global__ void scanB(float* bsumL, float* bsumN){
  int t=threadIdx.x;
  if(t<3){ float r=0; for(int i=0;i<64;i++){ float v=bsumL[t*64+i]; bsumL[t*64+i]=r; r+=v; } }
  else if(t<6){ int j=t-3; float r=0; for(int i=0;i<128;i++){ float v=bsumN[j*128+i]; bsumN[j*128+i]=r; r+=v; } }
}

__global__ void inside_eval(const uint2* __restrict__ accF, const float* __restrict__ alt,
                            const u16* __restrict__ usize16, const float* __restrict__ leafM,
                            const float* __restrict__ bsumL, float* __restrict__ out, int j0){
  int a=L_VERTS + blockIdx.x*blockDim.x+threadIdx.x;
  if(a>=N_NODES) return;
  u32 lo=accF[a].x;
  u32 hi=lo + (u32)usize16[a] + 1u;
  float u=alt[a];
  float up=1.f; for(int i=0;i<j0;i++) up*=u;
  float acc=0.f;
  #pragma unroll
  for(int j=0;j<3;j++){
    const float* arr=leafM + (size_t)j*L_VERTS;
    const float* bs=bsumL + j*64;
    float Ph = arr[hi-1u] + bs[(hi-1u)>>10];
    float Pl = lo ? (arr[lo-1u] + bs[(lo-1u)>>10]) : 0.f;
    acc += up*(Ph-Pl);
    up*=u;
  }
  out[a]+=acc;
}

__global__ void outside_eval(const uint2* __restrict__ accF, const float* __restrict__ alt,
                             const float* __restrict__ nodeM, const float* __restrict__ bsumN,
                             float* __restrict__ out, int j0){
  int n=blockIdx.x*blockDim.x+threadIdx.x;
  if(n>=N_NODES) return;
  u32 q=accF[n].y;
  float u=alt[n];
  float up=1.f; for(int i=0;i<j0;i++) up*=u;
  float acc=0.f;
  #pragma unroll
  for(int j=0;j<3;j++){
    float T = nodeM[(size_t)j*NODEPAD+q] + bsumN[j*128 + (q>>10)];
    acc += up*T;
    up*=u;
  }
  out[n]+=acc;
}

__global__ void ws_too_small(float* out){
  int i=blockIdx.x*blockDim.x+threadIdx.x;
  if(i<N_NODES) out[i]=1.0e6f;
}

// ---------------- launch ----------------
extern "C" void kernel_launch(void* const* d_in, const int* in_sizes, int n_in,
                              void* d_out, int out_size, void* d_ws, size_t ws_size,
                              hipStream_t stream){
  (void)in_sizes; (void)n_in; (void)out_size;
  const float* w  = (const float*)d_in[0];
  const int* src  = (const int*)d_in[1];
  const int* dst  = (const int*)d_in[2];
  float* out = (float*)d_out;

  char* ws = (char*)d_ws;
  size_t off=0;
  auto alloc=[&](size_t bytes)->void*{ void* p = ws+off; off += (bytes+511)&~(size_t)511; return p; };
  // persistent
  u32* parent   =(u32*)alloc((size_t)N_NODES*4);
  float* alt    =(float*)alloc((size_t)N_NODES*4);
  u16* usize16  =(u16*)alloc((size_t)N_NODES*2);
  u32* diag     =(u32*)alloc(512);
  float* bsumL  =(float*)alloc(3*64*4);
  float* bsumN  =(float*)alloc(3*128*4);
  size_t scratch0=off;
  // phase A (sort + build) — dead after p3/verify
  u32* keys0    =(u32*)alloc((size_t)N_EDGES*4); // after sort: epair; after p1: outChB16+outSize16
  u32* vals0    =(u32*)alloc((size_t)N_EDGES*4); // sorted order (alive through P3)
  u32* vals1    =(u32*)alloc((size_t)N_EDGES*4); // sort scratch -> lid16
  u32* histG    =(u32*)alloc(256*NB*4);          // dead after sort -> outChA16
  u16* canonTop16=(u16*)alloc((size_t)L_VERTS*2);
  u16* outJ16   =(u16*)alloc((size_t)N_EDGES*2);
  u16* svroot16 =(u16*)alloc((size_t)CCH*MAXSV*2);
  u16* svsize16 =(u16*)alloc((size_t)CCH*MAXSV*2); // dead after P2 load -> compR16
  u16* svnext16 =(u16*)alloc((size_t)CCH*MAXSV*2); // dead after P2 load -> compTop16
  u32* mG       =(u32*)alloc(CCH*4);
  u32* accCnt   =(u32*)alloc(CCH*4);
  u32* ncomp    =(u32*)alloc(CCH*4);
  size_t endA=off;
  // phase B (poly softarea) — overlays phase A scratch
  off=scratch0;
  u32* ccChsum  =(u32*)alloc((size_t)L_VERTS*4);     // verify chsum -> childCnt
  u32* J0       =(u32*)alloc((size_t)N_NODES*4);
  u32* J1       =(u32*)alloc((size_t)N_NODES*4);
  uint2* A0     =(uint2*)alloc((size_t)N_NODES*8);
  uint2* A1     =(uint2*)alloc((size_t)N_NODES*8);
  float* leafM  =(float*)alloc((size_t)3*L_VERTS*4);
  float* nodeM  =(float*)alloc((size_t)3*NODEPAD*4);
  size_t endB=off;

  if((endA>ws_size)||(endB>ws_size)){
    ws_too_small<<<(N_NODES+255)/256,256,0,stream>>>(out);
    return;
  }

  u16* lid16    =(u16*)vals1;
  u32* epair    =keys0;                          // keys dead after sort; p1-only
  u16* outChA16 =(u16*)histG;
  u16* outChB16 =(u16*)keys0;                    // written by p2 (after p1 done)
  u16* outSize16=(u16*)((char*)keys0 + (size_t)N_EDGES*2);
  u16* compR16  =svsize16;
  u16* compTop16=svnext16;
  u32* chsum    =ccChsum;
  u32* szG      =(u32*)usize16;                  // u32[L_VERTS] aliases usize16 region

  // --- sort ---
  init_keys<<<(N_EDGES+255)/256,256,0,stream>>>(w,keys0,vals0);
  for(int pass=0;pass<4;pass++){
    const u32* iv = (pass&1)?vals1:vals0;
    u32* ov = (pass&1)?vals0:vals1;
    int shift=pass*8;
    radix_hist   <<<NB,TPB,0,stream>>>(iv,keys0,histG,shift);
    radix_scan   <<<1,1024,0,stream>>>(histG);
    radix_scatter<<<NB,TPB,0,stream>>>(iv,keys0,ov,histG,shift);
  }
  // --- tree build ---
  build_epair<<<(N_EDGES+255)/256,256,0,stream>>>(vals0,src,dst,epair);
  init_all<<<(N_NODES+255)/256,256,0,stream>>>(szG,canonTop16,parent,alt);
  p1_checkpoints<<<1,1024,0,stream>>>(epair,szG,lid16,svroot16,svsize16,svnext16,mG);
  p2_chunk<<<CCH,64,0,stream>>>(lid16,svsize16,svnext16,mG,
                                outChA16,outChB16,outSize16,outJ16,accCnt,compR16,compTop16,ncomp);
  p3_stitch<<<1,1024,0,stream>>>(accCnt,outChA16,outChB16,outSize16,outJ16,svroot16,
                                 compR16,compTop16,ncomp,vals0,w,canonTop16,parent,alt,usize16,diag);
  // --- verify (also zeroes cc) ---
  verify_zero <<<(L_VERTS+255)/256,256,0,stream>>>(chsum,diag);
  verify_pass1<<<(N_NODES+255)/256,256,0,stream>>>(parent,alt,usize16,chsum,diag);
  verify_pass2<<<(L_VERTS+255)/256,256,0,stream>>>(usize16,chsum,diag);
  // --- DFS coordinates via fused pointer doubling (9 launches = 18 rounds) ---
  prep_init<<<(N_NODES+255)/256,256,0,stream>>>(parent,usize16,ccChsum,J0,A0,out);
  for(int r=0;r<9;r++){
    if((r&1)==0) double_round2<<<(N_NODES+255)/256,256,0,stream>>>(J0,A0,J1,A1);
    else         double_round2<<<(N_NODES+255)/256,256,0,stream>>>(J1,A1,J0,A0);
  }
  const uint2* accF=A1;  // 9 launches (odd) -> final in A1
  // --- two moment batches: j0=0 (h0..h2), j0=3 (h3..h5) ---
  for(int j0=0;j0<=3;j0+=3){
    zero_nodeM<<<(3*NODEPAD+255)/256,256,0,stream>>>(nodeM);
    leaf_scatter<<<(L_VERTS+255)/256,256,0,stream>>>(parent,alt,accF,leafM,j0);
    node_scatter<<<(N_NODES+255)/256,256,0,stream>>>(parent,alt,usize16,accF,nodeM,j0);
    scanA<<<dim3(64,3),256,0,stream>>>(leafM,L_VERTS,bsumL);
    scanA<<<dim3(128,3),256,0,stream>>>(nodeM,NODEPAD,bsumN);
    scanB<<<1,64,0,stream>>>(bsumL,bsumN);
    inside_eval<<<(L_VERTS+255)/256,256,0,stream>>>(accF,alt,usize16,leafM,bsumL,out,j0);
    outside_eval<<<(N_NODES+255)/256,256,0,stream>>>(accF,alt,nodeM,bsumN,out,j0);
  }
  fixup<<<(N_NODES+255)/256,256,0,stream>>>(diag,out);
}

// Round 9
// 2987.995 us; speedup vs baseline: 43.9874x; 1.0758x over previous
//
#include <hip/hip_runtime.h>
#include <stdint.h>

typedef unsigned int u32;
typedef unsigned short u16;

#define L_VERTS 65536
#define N_EDGES 130560
#define N_NODES 131071   // 2*L - 1
#define NODEPAD 131072

// chunked-parallel tree build: 170 chunks x 768 edges = 130560
#define CCH 170
#define SCH 768
#define MAXSV 1536
#define HSZ 2048

// ---------------- radix sort (stable LSD, index ping-pong, gathered keys) ----
#define NB 255
#define TPB 64
#define IPT 8
#define IPB 512

__global__ void init_keys(const float* __restrict__ w, u32* __restrict__ keys, u32* __restrict__ vals){
  int i = blockIdx.x*blockDim.x + threadIdx.x;
  if(i < N_EDGES){ keys[i] = __float_as_uint(w[i]); vals[i] = (u32)i; } // w>=0 -> uint order == float order
}

__global__ void radix_hist(const u32* __restrict__ idx, const u32* __restrict__ keys,
                           u32* __restrict__ histG, int shift){
  __shared__ u32 h[256];
  for(int i=threadIdx.x;i<256;i+=TPB) h[i]=0;
  __syncthreads();
  int base = blockIdx.x*IPB + threadIdx.x*IPT;
  #pragma unroll
  for(int i=0;i<IPT;i++){
    u32 e = idx[base+i];
    u32 d = (keys[e]>>shift)&255u;
    atomicAdd(&h[d],1u);
  }
  __syncthreads();
  for(int i=threadIdx.x;i<256;i+=TPB) histG[i*NB+blockIdx.x]=h[i];  // digit-major
}

__global__ void radix_scan(u32* histG){
  const int M = 256*NB;
  __shared__ u32 sums[1024];
  int t=threadIdx.x; int s=t*64; u32 acc=0;
  for(int i=0;i<64;i++){int id=s+i; if(id<M) acc+=histG[id];}
  sums[t]=acc; __syncthreads();
  for(int off=1; off<1024; off<<=1){
    u32 v=(t>=off)?sums[t-off]:0u;
    __syncthreads();
    sums[t]+=v;
    __syncthreads();
  }
  u32 run = (t==0)?0u:sums[t-1];
  for(int i=0;i<64;i++){int id=s+i; if(id<M){u32 v=histG[id]; histG[id]=run; run+=v;}}
}

__global__ void radix_scatter(const u32* __restrict__ idxIn, const u32* __restrict__ keys,
                              u32* __restrict__ idxOut, const u32* __restrict__ histG, int shift){
  __shared__ u16 thoff[256][TPB];
  int t=threadIdx.x;
  for(int d=t;d<256;d+=TPB) for(int j=0;j<TPB;j++) thoff[d][j]=0;
  __syncthreads();
  int base = blockIdx.x*IPB + t*IPT;
  u32 myv[IPT]; u32 myd[IPT];
  #pragma unroll
  for(int i=0;i<IPT;i++){
    myv[i]=idxIn[base+i];
    myd[i]=(keys[myv[i]]>>shift)&255u;
    thoff[myd[i]][t]++;
  }
  __syncthreads();
  for(int dd=0;dd<4;dd++){
    int d=t*4+dd; u32 run=0;
    for(int j=0;j<TPB;j++){ u32 v=thoff[d][j]; thoff[d][j]=(u16)run; run+=v; }
  }
  __syncthreads();
  #pragma unroll
  for(int i=0;i<IPT;i++){
    u32 d=myd[i];
    u32 pos = histG[d*NB+blockIdx.x] + (u32)thoff[d][t];
    thoff[d][t]++;                       // stable within thread
    idxOut[pos]=myv[i];
  }
}

// epair[p] = (dst<<16)|src for sorted position p
__global__ void build_epair(const u32* __restrict__ order, const int* __restrict__ srcv,
                            const int* __restrict__ dstv, u32* __restrict__ epair){
  int p=blockIdx.x*blockDim.x+threadIdx.x;
  if(p>=N_EDGES) return;
  u32 e=order[p];
  epair[p]=((u32)dstv[e]<<16)|(u32)srcv[e];
}

// ---------------- init ----------------
__global__ void init_all(u32* szG,u16* canonTop16,u32* parent,float* alt){
  int i=blockIdx.x*blockDim.x+threadIdx.x;
  if(i<N_NODES){ parent[i]=(u32)i; alt[i]=0.f; }
  if(i<L_VERTS){ szG[i]=1u; canonTop16[i]=0xFFFFu; }
}

__device__ __forceinline__ u32 ald(u32* p){
  return __hip_atomic_load(p, __ATOMIC_RELAXED, __HIP_MEMORY_SCOPE_AGENT);
}
__device__ __forceinline__ void ast(u32* p, u32 v){
  __hip_atomic_store(p, v, __ATOMIC_RELAXED, __HIP_MEMORY_SCOPE_AGENT);
}

// ---------------- P1: checkpoints + global CC (1 block x 1024) ---------------
// Whole-graph UF in LDS (u16[65536]=128K). 6 barriers/chunk. szG reads pulled
// off the find/claim critical chain into a batched gathered loop. hval is a
// separate array (no alias) so slot arrays init merges into hash-init phase.
__global__ void __launch_bounds__(1024,1) p1_checkpoints(
    const u32* __restrict__ epair,
    u32* szG, u16* lid16, u16* svroot16, u16* svsize16, u16* svnext16, u32* mG)
{
  __shared__ u16 ufL[L_VERTS];     // 128 KB
  __shared__ u32 hkey[HSZ];        // 8 KB
  __shared__ u16 hval[HSZ];        // 4 KB
  __shared__ u32 sufL[MAXSV];      // 6 KB
  __shared__ u32 compsz[MAXSV];    // 6 KB
  __shared__ u32 repkey[MAXSV];    // 6 KB   (total ~158 KB + mcnt)
  __shared__ u32 mcnt;
  int t = threadIdx.x;
  for(int i=t;i<L_VERTS/2;i+=1024) ((u32*)ufL)[i]=((2u*(u32)i+1u)<<16)|(2u*(u32)i); // ufL[v]=v
  for(int k=0;k<CCH;k++){
    // phase0: init hash + slot arrays
    for(int i=t;i<HSZ;i+=1024) hkey[i]=0xFFFFFFFFu;
    for(u32 s=t;s<MAXSV;s+=1024){ sufL[s]=s; compsz[s]=0u; repkey[s]=0u; }
    if(t==0) mcnt=0u;
    __syncthreads();
    int base = k*SCH;
    // phase1: find + claim (no szG on critical path)
    int myslot[2]; int mycnt=0;
    for(int i=t;i<2*SCH;i+=1024){
      u32 pr = epair[base+(i>>1)];
      u32 v = (i&1)? (pr>>16) : (pr&0xFFFFu);
      u32 x=v;
      while(true){ u32 px=ufL[x]; if(px==x)break; u32 g=ufL[px]; if(g!=px) ufL[x]=(u16)g; x=g; }
      u32 r=x;
      if(v!=r) ufL[v]=(u16)r;       // direct compression (benign race; no hooks this phase)
      u32 h=(r*2654435761u)>>21;    // [0,2048)
      int slot;
      while(true){
        u32 old=atomicCAS(&hkey[h],0xFFFFFFFFu,r);
        if(old==0xFFFFFFFFu){
          slot=(int)h;
          u32 id=atomicAdd(&mcnt,1u);
          hval[h]=(u16)id;
          svroot16[k*MAXSV+id]=(u16)r;
          break;
        }
        if(old==r){slot=(int)h;break;}
        h=(h+1)&(HSZ-1u);
      }
      myslot[mycnt++]=slot;
    }
    __syncthreads();
    // phase2: batched szG gather + lid16 emission
    u32 mc=mcnt;
    if(t==0) mG[k]=mc;
    for(u32 s=t;s<mc;s+=1024){
      u32 r=(u32)svroot16[k*MAXSV+s];
      svsize16[k*MAXSV+s]=(u16)(ald(&szG[r])-1u);
    }
    {
      int c=0;
      for(int i=t;i<2*SCH;i+=1024){ lid16[2*base+i]=hval[myslot[c]]; c++; }
    }
    __syncthreads();
    // phase3: slot unions, all-LDS (min-id CAS hooks => acyclic)
    for(int i=t;i<SCH;i+=1024){
      u32 lw=((u32*)lid16)[base+i];
      u32 sa=lw&0xFFFFu, sb=lw>>16;
      if(sa==sb) continue;
      while(true){
        u32 x=sa; while(true){u32 p2=sufL[x]; if(p2==x)break; u32 g=sufL[p2]; if(g!=p2) sufL[x]=g; x=g;}
        u32 y=sb; while(true){u32 p2=sufL[y]; if(p2==y)break; u32 g=sufL[p2]; if(g!=p2) sufL[y]=g; y=g;}
        if(x==y) break;
        u32 hi=x>y?x:y, lo=x^y^hi;
        if(atomicCAS(&sufL[hi],hi,lo)==hi) break;
        sa=hi; sb=lo;
      }
    }
    __syncthreads();
    // phase4: per-component aggregation (total size + rep = max size)
    for(u32 s=t;s<mc;s+=1024){
      u32 x=s; while(true){u32 p2=sufL[x]; if(p2==x)break; x=p2;}
      sufL[s]=x;                                  // values only decrease -> safe
      u32 sz=(u32)svsize16[k*MAXSV+s]+1u;
      atomicAdd(&compsz[x], sz);
      atomicMax(&repkey[x], (sz<<11) | (2047u-s));  // tie -> smallest slot
    }
    __syncthreads();
    // phase5: outputs + star hooks (rep root stays stable)
    for(u32 s=t;s<mc;s+=1024){
      u32 rs=sufL[s];
      u32 rep=2047u-(repkey[rs]&2047u);
      u32 wv=(u32)svroot16[k*MAXSV+rep];
      svnext16[k*MAXSV+s]=(u16)wv;
      u32 myroot=(u32)svroot16[k*MAXSV+s];
      if(myroot!=wv) ufL[myroot]=(u16)wv;         // star hook, one writer per root
      if(s==rep)     ast(&szG[wv], compsz[rs]);   // one writer per component
    }
    __syncthreads();
  }
}

// ---------------- P2: per-chunk local Kruskal (170 blocks) -------------------
__global__ void __launch_bounds__(64) p2_chunk(
  const u16* __restrict__ lid16,
  const u16* __restrict__ svsize16, const u16* __restrict__ svnext16, const u32* __restrict__ mG,
  u16* __restrict__ outChA, u16* __restrict__ outChB, u16* __restrict__ outSize16, u16* __restrict__ outJ16,
  u32* __restrict__ accCnt, u16* __restrict__ compR16, u16* __restrict__ compTop16, u32* __restrict__ ncomp)
{
  int k = blockIdx.x; int t = threadIdx.x;
  __shared__ u16 uf[MAXSV];
  __shared__ u32 csize[MAXSV];
  __shared__ u16 ctop[MAXSV];
  __shared__ u16 svnl[MAXSV];
  __shared__ u32 cmp_s;
  u32 m = mG[k];
  for(u32 s=t;s<m;s+=64){
    uf[s]=(u16)s;
    csize[s]=(u32)svsize16[k*MAXSV+s]+1u;
    ctop[s]=(u16)s;
    svnl[s]=svnext16[k*MAXSV+s];
  }
  if(t==0) cmp_s=0u;
  __syncthreads();
  if(t==0){
    int base=k*SCH;
    u32 cnt=0;
    for(int j=0;j<SCH;j++){
      u32 lw = ((const u32*)lid16)[base+j];
      u32 la = lw & 0xFFFFu, lb = lw >> 16;
      u32 x=la; while(true){u32 px=uf[x]; if(px==x)break; u32 g=uf[px]; uf[x]=(u16)g; x=g;}
      u32 y=lb; while(true){u32 py=uf[y]; if(py==y)break; u32 g=uf[py]; uf[y]=(u16)g; y=g;}
      if(x==y) continue;
      u32 sa=csize[x], sb=csize[y], ns=sa+sb;
      outChA[base+cnt]=ctop[x];
      outChB[base+cnt]=ctop[y];
      outSize16[base+cnt]=(u16)(ns-1u);
      outJ16[base+cnt]=(u16)j;
      u32 win=(sa>=sb)?x:y, los=x^y^win;
      uf[los]=(u16)win; csize[win]=ns; ctop[win]=(u16)(0x8000u|cnt);
      cnt++;
    }
    accCnt[k]=cnt;
  }
  __syncthreads();
  for(u32 s=t;s<m;s+=64){
    if(uf[s]==(u16)s && (ctop[s]&0x8000u)){
      u32 pos=atomicAdd(&cmp_s,1u);
      compR16[k*MAXSV+pos]=svnl[s];
      compTop16[k*MAXSV+pos]=(u16)(ctop[s]&0x7FFFu);
    }
  }
  __syncthreads();
  if(t==0) ncomp[k]=cmp_s;
}

// ---------------- P3: stitch (1 block x 1024) --------------------------------
__global__ void __launch_bounds__(1024) p3_stitch(
  const u32* __restrict__ accCnt, const u16* __restrict__ outChA, const u16* __restrict__ outChB,
  const u16* __restrict__ outSize16, const u16* __restrict__ outJ16,
  const u16* __restrict__ svroot16,
  const u16* __restrict__ compR16, const u16* __restrict__ compTop16, const u32* __restrict__ ncomp,
  const u32* __restrict__ order, const float* __restrict__ w,
  u16* __restrict__ canonTop16, u32* __restrict__ parent, float* __restrict__ alt, u16* __restrict__ usize16)
{
  __shared__ u32 accBase[CCH];
  int t=threadIdx.x;
  if(t==0){ u32 r=0; for(int k=0;k<CCH;k++){ accBase[k]=r; r+=accCnt[k]; } }
  __syncthreads();
  for(int idx=t; idx<N_EDGES; idx+=1024){
    int k = idx/SCH; int j = idx - k*SCH;
    if(j < (int)accCnt[k]){
      u32 nid = (u32)L_VERTS + accBase[k] + (u32)j;
      u32 p = (u32)(k*SCH) + (u32)outJ16[idx];
      alt[nid] = w[order[p]];
      usize16[nid] = outSize16[idx];
      u32 cA=outChA[idx]; if(cA & 0x8000u) parent[(u32)L_VERTS+accBase[k]+(cA&0x7FFFu)] = nid;
      u32 cB=outChB[idx]; if(cB & 0x8000u) parent[(u32)L_VERTS+accBase[k]+(cB&0x7FFFu)] = nid;
    }
  }
  __syncthreads();
  for(int k=0;k<CCH;k++){
    u32 ac=accCnt[k];
    for(u32 j=t;j<ac;j+=1024){
      u32 idx=(u32)(k*SCH)+j;
      u32 nid=(u32)L_VERTS+accBase[k]+j;
      u32 cA=outChA[idx];
      if(!(cA&0x8000u)){
        u32 root=(u32)svroot16[k*MAXSV+cA];
        u32 ct=(u32)canonTop16[root];
        parent[(ct==0xFFFFu)?root:((u32)L_VERTS+ct)]=nid;
      }
      u32 cB=outChB[idx];
      if(!(cB&0x8000u)){
        u32 root=(u32)svroot16[k*MAXSV+cB];
        u32 ct=(u32)canonTop16[root];
        parent[(ct==0xFFFFu)?root:((u32)L_VERTS+ct)]=nid;
      }
    }
    __syncthreads();
    u32 nc=ncomp[k];
    for(u32 j=t;j<nc;j+=1024){
      canonTop16[(u32)compR16[k*MAXSV+j]] = (u16)(accBase[k]+compTop16[k*MAXSV+j]);
    }
    __syncthreads();
  }
}

// ---------------- softarea via degree-5 sigmoid poly + DFS intervals ---------
__device__ __forceinline__ void hvals3(float v, int j0, float* o){
  float v2=v*v, v3=v2*v, v4=v2*v2, v5=v4*v;
  if(j0==0){
    o[0]=0.5f-0.25f*v+v3*(1.f/48.f)-v5*(1.f/480.f);
    o[1]=0.25f-v2*(1.f/16.f)+v4*(1.f/96.f);
    o[2]=v*(1.f/16.f)-v3*(1.f/48.f);
  }else{
    o[0]=v2*(1.f/48.f)-(1.f/48.f);
    o[1]=-v*(1.f/96.f);
    o[2]=(1.f/480.f);
  }
}

__global__ void zero_cc(u32* cc){
  int i=blockIdx.x*blockDim.x+threadIdx.x;
  if(i<L_VERTS) cc[i]=0u;
}

// prep: out init; per-node downward-prefix seeds (leafLo, preOrd) + J=parent
__global__ void prep_init(const u32* __restrict__ parent, const u16* __restrict__ usize16,
                          u32* cc, u32* J0, uint2* A0, float* out){
  int n=blockIdx.x*blockDim.x+threadIdx.x;
  if(n>=N_NODES) return;
  out[n] = (n<L_VERTS)?0.5f:0.0f;
  if(n==N_NODES-1){ J0[n]=(u32)n; A0[n]=make_uint2(0u,0u); return; }  // root
  u32 p=parent[n];
  u32 ord=atomicAdd(&cc[p-L_VERTS],1u);          // 0 or 1: child order
  u32 szP=(u32)usize16[p]+1u;
  u32 szN=(n<L_VERTS)?1u:((u32)usize16[n]+1u);
  u32 sib=szP-szN;
  A0[n]=make_uint2(ord? sib:0u, 1u + (ord? (2u*sib-1u):0u));
  J0[n]=p;
}

// fused pointer doubling, 2 rounds per launch
__global__ void double_round2(const u32* __restrict__ Jin, const uint2* __restrict__ Ain,
                              u32* __restrict__ Jout, uint2* __restrict__ Aout){
  int n=blockIdx.x*blockDim.x+threadIdx.x;
  if(n>=N_NODES) return;
  u32 j=Jin[n];
  u32 j2=Jin[j];
  u32 j3=Jin[j2];
  uint2 a=Ain[n], aj=Ain[j], b=Ain[j2], bj=Ain[j3];
  Aout[n]=make_uint2(a.x+aj.x+b.x+bj.x, a.y+aj.y+b.y+bj.y);
  Jout[n]=Jin[j3];
}

__global__ void zero_nodeM(float* nodeM){
  int i=blockIdx.x*blockDim.x+threadIdx.x;
  if(i<3*NODEPAD) nodeM[i]=0.f;
}

// fused scatter: leaf h-values (n<L) + node interval terms (n<N-1).
// Both use h_j(alt(parent(n))) — one hvals3 per node.
__global__ void scatter_all(const u32* __restrict__ parent, const float* __restrict__ alt,
                            const u16* __restrict__ usize16, const uint2* __restrict__ accF,
                            float* __restrict__ leafM, float* __restrict__ nodeM, int j0){
  int n=blockIdx.x*blockDim.x+threadIdx.x;
  if(n>=N_NODES) return;
  u32 p=parent[n];                 // root: p==n, handled below
  float h[3]; hvals3(alt[p],j0,h);
  uint2 af=accF[n];
  if(n<L_VERTS){
    u32 pos=af.x;
    leafM[0*L_VERTS+pos]=h[0];
    leafM[1*L_VERTS+pos]=h[1];
    leafM[2*L_VERTS+pos]=h[2];
  }
  if(n<N_NODES-1){
    u32 szP=(u32)usize16[p]+1u;
    u32 szN=(n<L_VERTS)?1u:((u32)usize16[n]+1u);
    float d=(float)(szP-szN);
    u32 q0=af.y;
    u32 q1=q0 + 2u*szN - 1u;
    #pragma unroll
    for(int j=0;j<3;j++){
      float tm=d*h[j];
      atomicAdd(&nodeM[j*NODEPAD+q0], tm);
      atomicAdd(&nodeM[j*NODEPAD+q1], -tm);
    }
  }
}

// one dispatch scans all 6 rows: 3 leaf rows (64 blocks) + 3 node rows (128)
__global__ void scanAll(float* __restrict__ leafM, float* __restrict__ nodeM,
                        float* __restrict__ bsumL, float* __restrict__ bsumN){
  int b=blockIdx.x; int t=threadIdx.x;
  float* arr; u32 base; float* bs;
  if(b<3*64){ int row=b>>6, blk=b&63;  arr=leafM+(size_t)row*L_VERTS;  base=(u32)blk*1024u; bs=&bsumL[row*64+blk]; }
  else      { int bb=b-192; int row=bb>>7, blk=bb&127; arr=nodeM+(size_t)row*NODEPAD; base=(u32)blk*1024u; bs=&bsumN[row*128+blk]; }
  __shared__ float s[256];
  base += (u32)t*4u;
  float v0=arr[base],v1=arr[base+1],v2=arr[base+2],v3=arr[base+3];
  v1+=v0; v2+=v1; v3+=v2;
  s[t]=v3; __syncthreads();
  for(int o=1;o<256;o<<=1){ float x=(t>=o)?s[t-o]:0.f; __syncthreads(); s[t]+=x; __syncthreads(); }
  float pre=(t>0)?s[t-1]:0.f;
  arr[base]=v0+pre; arr[base+1]=v1+pre; arr[base+2]=v2+pre; arr[base+3]=v3+pre;
  if(t==255) *bs=s[255];
}

__global__ void scanB(float* bsumL, float* bsumN){
  int t=threadIdx.x;
  if(t<3){ float r=0; for(int i=0;i<64;i++){ float v=bsumL[t*64+i]; bsumL[t*64+i]=r; r+=v; } }
  else if(t<6){ int j=t-3; float r=0; for(int i=0;i<128;i++){ float v=bsumN[j*128+i]; bsumN[j*128+i]=r; r+=v; } }
}

// fused eval: outside for all n, inside for internal nodes
__global__ void eval_all(const uint2* __restrict__ accF, const float* __restrict__ alt,
                         const u16* __restrict__ usize16, const float* __restrict__ leafM,
                         const float* __restrict__ nodeM, const float* __restrict__ bsumL,
                         const float* __restrict__ bsumN, float* __restrict__ out, int j0){
  int n=blockIdx.x*blockDim.x+threadIdx.x;
  if(n>=N_NODES) return;
  uint2 af=accF[n];
  float u=alt[n];
  float up0=1.f; for(int i=0;i<j0;i++) up0*=u;
  u32 q=af.y;
  float acc=0.f, up=up0;
  #pragma unroll
  for(int j=0;j<3;j++){
    float T = nodeM[(size_t)j*NODEPAD+q] + bsumN[j*128 + (q>>10)];
    acc += up*T;
    up*=u;
  }
  if(n>=L_VERTS){
    u32 lo=af.x;
    u32 hi=lo + (u32)usize16[n] + 1u;
    up=up0;
    #pragma unroll
    for(int j=0;j<3;j++){
      const float* arr=leafM + (size_t)j*L_VERTS;
      const float* bs=bsumL + j*64;
      float Ph = arr[hi-1u] + bs[(hi-1u)>>10];
      float Pl = lo ? (arr[lo-1u] + bs[(lo-1u)>>10]) : 0.f;
      acc += up*(Ph-Pl);
      up*=u;
    }
  }
  out[n]+=acc;
}

__global__ void ws_too_small(float* out){
  int i=blockIdx.x*blockDim.x+threadIdx.x;
  if(i<N_NODES) out[i]=1.0e6f;
}

// ---------------- launch ----------------
extern "C" void kernel_launch(void* const* d_in, const int* in_sizes, int n_in,
                              void* d_out, int out_size, void* d_ws, size_t ws_size,
                              hipStream_t stream){
  (void)in_sizes; (void)n_in; (void)out_size;
  const float* w  = (const float*)d_in[0];
  const int* src  = (const int*)d_in[1];
  const int* dst  = (const int*)d_in[2];
  float* out = (float*)d_out;

  char* ws = (char*)d_ws;
  size_t off=0;
  auto alloc=[&](size_t bytes)->void*{ void* p = ws+off; off += (bytes+511)&~(size_t)511; return p; };
  // persistent
  u32* parent   =(u32*)alloc((size_t)N_NODES*4);
  float* alt    =(float*)alloc((size_t)N_NODES*4);
  u16* usize16  =(u16*)alloc((size_t)N_NODES*2);
  float* bsumL  =(float*)alloc(3*64*4);
  float* bsumN  =(float*)alloc(3*128*4);
  size_t scratch0=off;
  // phase A (sort + build) — dead after p3
  u32* keys0    =(u32*)alloc((size_t)N_EDGES*4); // after sort: epair; after p1: outChB16+outSize16
  u32* vals0    =(u32*)alloc((size_t)N_EDGES*4); // sorted order (alive through P3)
  u32* vals1    =(u32*)alloc((size_t)N_EDGES*4); // sort scratch -> lid16
  u32* histG    =(u32*)alloc(256*NB*4);          // dead after sort -> outChA16
  u16* canonTop16=(u16*)alloc((size_t)L_VERTS*2);
  u16* outJ16   =(u16*)alloc((size_t)N_EDGES*2);
  u16* svroot16 =(u16*)alloc((size_t)CCH*MAXSV*2);
  u16* svsize16 =(u16*)alloc((size_t)CCH*MAXSV*2); // dead after P2 load -> compR16
  u16* svnext16 =(u16*)alloc((size_t)CCH*MAXSV*2); // dead after P2 load -> compTop16
  u32* mG       =(u32*)alloc(CCH*4);
  u32* accCnt   =(u32*)alloc(CCH*4);
  u32* ncomp    =(u32*)alloc(CCH*4);
  size_t endA=off;
  // phase B (poly softarea) — overlays phase A scratch
  off=scratch0;
  u32* ccChsum  =(u32*)alloc((size_t)L_VERTS*4);     // childCnt for prep_init
  u32* J0       =(u32*)alloc((size_t)N_NODES*4);
  u32* J1       =(u32*)alloc((size_t)N_NODES*4);
  uint2* A0     =(uint2*)alloc((size_t)N_NODES*8);
  uint2* A1     =(uint2*)alloc((size_t)N_NODES*8);
  float* leafM  =(float*)alloc((size_t)3*L_VERTS*4);
  float* nodeM  =(float*)alloc((size_t)3*NODEPAD*4);
  size_t endB=off;

  if((endA>ws_size)||(endB>ws_size)){
    ws_too_small<<<(N_NODES+255)/256,256,0,stream>>>(out);
    return;
  }

  u16* lid16    =(u16*)vals1;
  u32* epair    =keys0;                          // keys dead after sort; p1-only
  u16* outChA16 =(u16*)histG;
  u16* outChB16 =(u16*)keys0;                    // written by p2 (after p1 done)
  u16* outSize16=(u16*)((char*)keys0 + (size_t)N_EDGES*2);
  u16* compR16  =svsize16;
  u16* compTop16=svnext16;
  u32* szG      =(u32*)usize16;                  // u32[L_VERTS] aliases usize16 region

  // --- sort ---
  init_keys<<<(N_EDGES+255)/256,256,0,stream>>>(w,keys0,vals0);
  for(int pass=0;pass<4;pass++){
    const u32* iv = (pass&1)?vals1:vals0;
    u32* ov = (pass&1)?vals0:vals1;
    int shift=pass*8;
    radix_hist   <<<NB,TPB,0,stream>>>(iv,keys0,histG,shift);
    radix_scan   <<<1,1024,0,stream>>>(histG);
    radix_scatter<<<NB,TPB,0,stream>>>(iv,keys0,ov,histG,shift);
  }
  // --- tree build ---
  build_epair<<<(N_EDGES+255)/256,256,0,stream>>>(vals0,src,dst,epair);
  init_all<<<(N_NODES+255)/256,256,0,stream>>>(szG,canonTop16,parent,alt);
  p1_checkpoints<<<1,1024,0,stream>>>(epair,szG,lid16,svroot16,svsize16,svnext16,mG);
  p2_chunk<<<CCH,64,0,stream>>>(lid16,svsize16,svnext16,mG,
                                outChA16,outChB16,outSize16,outJ16,accCnt,compR16,compTop16,ncomp);
  p3_stitch<<<1,1024,0,stream>>>(accCnt,outChA16,outChB16,outSize16,outJ16,svroot16,
                                 compR16,compTop16,ncomp,vals0,w,canonTop16,parent,alt,usize16);
  // --- DFS coordinates via fused pointer doubling (9 launches = 18 rounds) ---
  zero_cc<<<(L_VERTS+255)/256,256,0,stream>>>(ccChsum);
  prep_init<<<(N_NODES+255)/256,256,0,stream>>>(parent,usize16,ccChsum,J0,A0,out);
  for(int r=0;r<9;r++){
    if((r&1)==0) double_round2<<<(N_NODES+255)/256,256,0,stream>>>(J0,A0,J1,A1);
    else         double_round2<<<(N_NODES+255)/256,256,0,stream>>>(J1,A1,J0,A0);
  }
  const uint2* accF=A1;  // 9 launches (odd) -> final in A1
  // --- two moment batches: j0=0 (h0..h2), j0=3 (h3..h5) ---
  for(int j0=0;j0<=3;j0+=3){
    zero_nodeM<<<(3*NODEPAD+255)/256,256,0,stream>>>(nodeM);
    scatter_all<<<(N_NODES+255)/256,256,0,stream>>>(parent,alt,usize16,accF,leafM,nodeM,j0);
    scanAll<<<576,256,0,stream>>>(leafM,nodeM,bsumL,bsumN);
    scanB<<<1,64,0,stream>>>(bsumL,bsumN);
    eval_all<<<(N_NODES+255)/256,256,0,stream>>>(accF,alt,usize16,leafM,nodeM,bsumL,bsumN,out,j0);
  }
}